// Round 19
// baseline (290.881 us; speedup 1.0000x reference)
//
#include <hip/hip_runtime.h>
#include <hip/hip_bf16.h>

typedef __attribute__((ext_vector_type(8))) short bfrag8;           // 8 bf16
typedef __attribute__((ext_vector_type(8))) unsigned short u16x8;
typedef __attribute__((ext_vector_type(4))) float f32x4;
typedef __attribute__((ext_vector_type(16))) float f32x16;          // 32x32 MFMA C/D
typedef __attribute__((ext_vector_type(4))) unsigned int u32x4;

static constexpr int L_ = 2048;
static constexpr int H_ = 16;
static constexpr int D_ = 64;
static constexpr int ROWSTRIDE = H_ * D_;
static constexpr int BSTRIDE = L_ * H_ * D_;
static constexpr size_t NPH = (size_t)L_ * D_;
static constexpr size_t NTOT = (size_t)4 * H_ * L_ * D_;

// Finite "minus infinity" for masking (exp2(NEG - FIXM) == 0 exactly).
static constexpr float NEG = -1e30f;
// Fixed softmax reference max (exp2 domain); normalizer cancels in O = PV/l.
static constexpr float FIXM = 24.0f;

__device__ __forceinline__ unsigned short f2bf(float f) {
  return __builtin_bit_cast(unsigned short, __float2bfloat16(f));
}
__device__ __forceinline__ unsigned int pack2(float lo, float hi) {
  return (unsigned int)f2bf(lo) | ((unsigned int)f2bf(hi) << 16);
}

// Cross-half (lane i <-> i+32) sum via permlane32_swap builtin (verified r6).
__device__ __forceinline__ float crosshalf_sum(float x) {
  const unsigned xu = __builtin_bit_cast(unsigned int, x);
  auto r = __builtin_amdgcn_permlane32_swap(xu, xu, false, false);
  return __builtin_bit_cast(float, (unsigned int)r[0]) +
         __builtin_bit_cast(float, (unsigned int)r[1]);
}

// ---------------------------------------------------------------------------
// Prep: f32 [B,L,H,D] -> bf16 Qb[B,H,L,D] (x 0.125*log2e), Kb[B,H,L,D],
// Vt[B,H,D,L].  Scores then live in exp2 domain.
// ---------------------------------------------------------------------------
__global__ __launch_bounds__(256, 4)
void prep_kernel(const float* __restrict__ Q, const float* __restrict__ K,
                 const float* __restrict__ V, unsigned short* __restrict__ Qb,
                 unsigned short* __restrict__ Kb, unsigned short* __restrict__ Vt) {
  const int bid = blockIdx.x;
  const int lt = bid & 31;
  const int bh = bid >> 5;
  const int h = bh & 15;
  const int b = bh >> 4;
  const int l0 = lt * 64;
  const int t = threadIdx.x;
  const int lr = t >> 2;
  const int dc = t & 3;

  __shared__ __align__(16) unsigned short vt[64 * 64];

  const size_t src = ((size_t)(b * L_ + l0 + lr) * H_ + h) * D_ + dc * 16;
  const size_t dst = ((size_t)bh * L_ + l0 + lr) * D_ + dc * 16;

  constexpr float QS = 0.125f * 1.44269504088896341f;   // (1/sqrt(D)) * log2(e)

  {
    f32x4 a = *(const f32x4*)(Q + src),     b4 = *(const f32x4*)(Q + src + 4),
          c4 = *(const f32x4*)(Q + src + 8), d4 = *(const f32x4*)(Q + src + 12);
    u16x8 o0, o1;
#pragma unroll
    for (int j = 0; j < 4; ++j) {
      o0[j] = f2bf(a[j] * QS);  o0[j + 4] = f2bf(b4[j] * QS);
      o1[j] = f2bf(c4[j] * QS); o1[j + 4] = f2bf(d4[j] * QS);
    }
    *(u16x8*)(Qb + dst) = o0;
    *(u16x8*)(Qb + dst + 8) = o1;
  }
  {
    f32x4 a = *(const f32x4*)(K + src),     b4 = *(const f32x4*)(K + src + 4),
          c4 = *(const f32x4*)(K + src + 8), d4 = *(const f32x4*)(K + src + 12);
    u16x8 o0, o1;
#pragma unroll
    for (int j = 0; j < 4; ++j) {
      o0[j] = f2bf(a[j]);  o0[j + 4] = f2bf(b4[j]);
      o1[j] = f2bf(c4[j]); o1[j + 4] = f2bf(d4[j]);
    }
    *(u16x8*)(Kb + dst) = o0;
    *(u16x8*)(Kb + dst + 8) = o1;
  }
  {
    f32x4 a = *(const f32x4*)(V + src),     b4 = *(const f32x4*)(V + src + 4),
          c4 = *(const f32x4*)(V + src + 8), d4 = *(const f32x4*)(V + src + 12);
    u16x8 o0, o1;
#pragma unroll
    for (int j = 0; j < 4; ++j) {
      o0[j] = f2bf(a[j]);  o0[j + 4] = f2bf(b4[j]);
      o1[j] = f2bf(c4[j]); o1[j + 4] = f2bf(d4[j]);
    }
    const int r7 = (lr + (lr >> 3)) & 7;
    *(u16x8*)&vt[lr * 64 + (((dc * 2) ^ r7) * 8)] = o0;
    *(u16x8*)&vt[lr * 64 + (((dc * 2 + 1) ^ r7) * 8)] = o1;
  }
  __syncthreads();
  {
    const int d = t >> 2;
    const int lc = t & 3;
    const int ch = d >> 3, dl = d & 7;
    u16x8 o0, o1;
#pragma unroll
    for (int i = 0; i < 8; ++i) {
      const int r0 = lc * 16 + i;
      const int r1 = lc * 16 + 8 + i;
      o0[i] = vt[r0 * 64 + ((ch ^ ((r0 + (r0 >> 3)) & 7)) * 8) + dl];
      o1[i] = vt[r1 * 64 + ((ch ^ ((r1 + (r1 >> 3)) & 7)) * 8) + dl];
    }
    const size_t vd = ((size_t)bh * D_ + d) * L_ + l0 + lc * 16;
    *(u16x8*)(Vt + vd) = o0;
    *(u16x8*)(Vt + vd + 8) = o1;
  }
}

// ---------------------------------------------------------------------------
// Pair-block staged-LDS flash attention, fixed-max softmax, DOUBLE-BUFFERED
// pair staging + backfill grid.
// r16 retrospect: its regression was the single-buffer [compute|barrier|
// ds_write|barrier] serialization, NOT reuse-2 (staging is L2-resident).
// This kernel: block = 2 adjacent q-tiles {2p,2p+1}; 4 waves = q-tile x
// kv-parity -> every wave computes every iteration (no convoy idle).
// Each iteration stages a PAIR of kv-tiles into the ALTERNATE 16KB half of
// a 32KB double buffer with r15's proven schedule: issue global->regs early,
// compute current pair, write-late into other buffer, ONE barrier.
// 32KB/block -> 4 blocks/CU LDS cap; grid 2048 = 2x resident capacity ->
// 1024-block backfill queue sustains ~16 waves/CU (no decay tail).
// Longest-first (p = 31-idx). 2-way kv merge = pure adds (fixed scale).
// launch_bounds(256,4): VGPR 64. r17 ERRATUM: NEVER tighten the cap
// ((512,8)->VGPR32 spilled the accumulator, 14x slower). Spill tripwire:
// WRITE_SIZE >> 33MB.
// ---------------------------------------------------------------------------
__global__ __launch_bounds__(256, 4)
void mha_fwd_db2(const unsigned short* __restrict__ Qb,
                 const unsigned short* __restrict__ Kb,
                 const unsigned short* __restrict__ Vt,
                 float* __restrict__ Op) {
  const int bid = blockIdx.x;
  const int plane = bid & 63;               // b*16 + h
  const int p = 31 - (bid >> 6);            // q-tile pair index, longest first
  const int h = plane & 15;
  const int b = plane >> 4;

  const int tid = threadIdx.x;
  const int wv = tid >> 6;
  const int qsel = wv >> 1;                 // 0 -> qt=2p, 1 -> qt=2p+1
  const int pr = wv & 1;                    // kv-tile parity for this wave
  const int lane = tid & 63;
  const int q = lane & 31;
  const int hi = lane >> 5;

  const int qt = 2 * p + qsel;
  const int qr0 = qt * 32;
  const int P = p + 1;                      // iterations (2 kv-tiles each)

  // 32KB double-buffered pair staging; merge overlays after final barrier.
  // K[buf][tile] at (buf*2+tile)*4096 ; V at +16384.
  __shared__ __align__(16) unsigned char arena[32768];
  float* mrg = (float*)arena;                          // [2][32][68] f32
  float* lshp = (float*)(arena + 17408);               // [2][32] f32

  const unsigned short* Qh = Qb + (size_t)plane * NPH;
  const unsigned short* Kh = Kb + (size_t)plane * NPH;
  const unsigned short* Vh = Vt + (size_t)plane * NPH;
  float* Ob = Op + (size_t)b * BSTRIDE + (size_t)h * D_;

  // staging roles (fixed per thread), XOR-chunk swizzle (write == read)
  const int kr = tid >> 3, kc = tid & 7;    // K: row 0..31, 16B chunk 0..7
  const int vr = tid >> 2, vc = tid & 3;    // V^T: row 0..63, 16B chunk 0..3
  const int kOff = kr * 64 + ((kc ^ (kr & 7)) * 8);
  const int vOff = vr * 32 + ((vc ^ (vr & 3)) * 8);
  // stage destinations: [buf][tile]
  unsigned short* kDst[2][2];
  unsigned short* vDst[2][2];
#pragma unroll
  for (int bu = 0; bu < 2; ++bu)
#pragma unroll
    for (int ti = 0; ti < 2; ++ti) {
      kDst[bu][ti] = (unsigned short*)(arena + (size_t)(bu * 2 + ti) * 4096) + kOff;
      vDst[bu][ti] = (unsigned short*)(arena + 16384 + (size_t)(bu * 2 + ti) * 4096) + vOff;
    }
  // compute-side bases for my parity: [buf]
  const unsigned short* kMy[2] = {
    (const unsigned short*)(arena + (size_t)(0 * 2 + pr) * 4096),
    (const unsigned short*)(arena + (size_t)(1 * 2 + pr) * 4096) };
  const unsigned short* vMy[2] = {
    (const unsigned short*)(arena + 16384 + (size_t)(0 * 2 + pr) * 4096),
    (const unsigned short*)(arena + 16384 + (size_t)(1 * 2 + pr) * 4096) };

  // Q B-frags: lane holds Q[qr0+q][16s + 8hi + j]
  bfrag8 qB[4];
#pragma unroll
  for (int s = 0; s < 4; ++s)
    qB[s] = *(const bfrag8*)(Qh + (qr0 + q) * D_ + 16 * s + 8 * hi);

  float lp = 0.f;
  f32x16 o0 = {};                            // O[q][d = crow + 0..31]
  f32x16 o1 = {};                            // O[q][d = crow + 32..63]

  // prologue: stage pair 0 (tiles 0,1) into buf 0
  {
    u16x8 k0 = *(const u16x8*)(Kh + (size_t)kr * D_ + kc * 8);
    u16x8 v0 = *(const u16x8*)(Vh + (size_t)vr * L_ + vc * 8);
    u16x8 k1 = *(const u16x8*)(Kh + (size_t)(32 + kr) * D_ + kc * 8);
    u16x8 v1 = *(const u16x8*)(Vh + (size_t)vr * L_ + 32 + vc * 8);
    *(u16x8*)kDst[0][0] = k0;  *(u16x8*)vDst[0][0] = v0;
    *(u16x8*)kDst[0][1] = k1;  *(u16x8*)vDst[0][1] = v1;
  }
  __syncthreads();

  for (int k = 0; k < P; ++k) {
    const int cur = k & 1;
    const int t = 2 * k + pr;                // my kv-tile this iteration
    const bool more = (k + 1 < P);

    // 1) issue next pair's global loads (land during compute below)
    u16x8 kn0, vn0, kn1, vn1;
    if (more) {
      const int base = (k + 1) * 64;         // rows of tile 2k+2
      kn0 = *(const u16x8*)(Kh + (size_t)(base + kr) * D_ + kc * 8);
      vn0 = *(const u16x8*)(Vh + (size_t)vr * L_ + base + vc * 8);
      kn1 = *(const u16x8*)(Kh + (size_t)(base + 32 + kr) * D_ + kc * 8);
      vn1 = *(const u16x8*)(Vh + (size_t)vr * L_ + base + 32 + vc * 8);
    }

    // 2) compute my tile (guard false only for wave (qsel0,pr1) at k=p)
    if (t <= qt) {
      const unsigned short* kb = kMy[cur];
      const unsigned short* vb = vMy[cur];
      bfrag8 kA[4];
#pragma unroll
      for (int s = 0; s < 4; ++s)
        kA[s] = *(const bfrag8*)&kb[q * 64 + (((2 * s + hi) ^ (q & 7)) * 8)];
      bfrag8 vA[2][2];
#pragma unroll
      for (int ks = 0; ks < 2; ++ks)
#pragma unroll
        for (int dh = 0; dh < 2; ++dh)
          vA[ks][dh] = *(const bfrag8*)&vb[(32 * dh + q) * 32 + (((2 * ks + hi) ^ (q & 3)) * 8)];

      f32x16 sacc = {};
      __builtin_amdgcn_s_setprio(1);
#pragma unroll
      for (int s = 0; s < 4; ++s)
        sacc = __builtin_amdgcn_mfma_f32_32x32x16_bf16(kA[s], qB[s], sacc, 0, 0, 0);
      __builtin_amdgcn_s_setprio(0);

      if (t == qt) {
#pragma unroll
        for (int r = 0; r < 16; ++r) {
          const int crow = (r & 3) + 8 * (r >> 2) + 4 * hi;
          if (crow > q) sacc[r] = NEG;
        }
      }

#pragma unroll
      for (int r = 0; r < 16; ++r) sacc[r] = __builtin_exp2f(sacc[r] - FIXM);
      {
        float s8[8];
#pragma unroll
        for (int r = 0; r < 8; ++r) s8[r] = sacc[2 * r] + sacc[2 * r + 1];
#pragma unroll
        for (int r = 0; r < 4; ++r) s8[r] += s8[r + 4];
        lp += (s8[0] + s8[2]) + (s8[1] + s8[3]);
      }

      const unsigned int a0 = pack2(sacc[0],  sacc[1]),  a1 = pack2(sacc[2],  sacc[3]);
      const unsigned int a2 = pack2(sacc[4],  sacc[5]),  a3 = pack2(sacc[6],  sacc[7]);
      const unsigned int a4 = pack2(sacc[8],  sacc[9]),  a5 = pack2(sacc[10], sacc[11]);
      const unsigned int a6 = pack2(sacc[12], sacc[13]), a7 = pack2(sacc[14], sacc[15]);
      auto r02 = __builtin_amdgcn_permlane32_swap(a0, a2, false, false);
      auto r13 = __builtin_amdgcn_permlane32_swap(a1, a3, false, false);
      auto r46 = __builtin_amdgcn_permlane32_swap(a4, a6, false, false);
      auto r57 = __builtin_amdgcn_permlane32_swap(a5, a7, false, false);
      u32x4 w0, w1;
      w0[0] = r02[0]; w0[1] = r13[0]; w0[2] = r02[1]; w0[3] = r13[1];
      w1[0] = r46[0]; w1[1] = r57[0]; w1[2] = r46[1]; w1[3] = r57[1];
      const bfrag8 pb0 = __builtin_bit_cast(bfrag8, w0);
      const bfrag8 pb1 = __builtin_bit_cast(bfrag8, w1);

      __builtin_amdgcn_s_setprio(1);
      o0 = __builtin_amdgcn_mfma_f32_32x32x16_bf16(vA[0][0], pb0, o0, 0, 0, 0);
      o0 = __builtin_amdgcn_mfma_f32_32x32x16_bf16(vA[1][0], pb1, o0, 0, 0, 0);
      o1 = __builtin_amdgcn_mfma_f32_32x32x16_bf16(vA[0][1], pb0, o1, 0, 0, 0);
      o1 = __builtin_amdgcn_mfma_f32_32x32x16_bf16(vA[1][1], pb1, o1, 0, 0, 0);
      __builtin_amdgcn_s_setprio(0);
    }

    // 3) write-late into the OTHER buffer (its readers finished last iter)
    if (more) {
      *(u16x8*)kDst[cur ^ 1][0] = kn0;  *(u16x8*)vDst[cur ^ 1][0] = vn0;
      *(u16x8*)kDst[cur ^ 1][1] = kn1;  *(u16x8*)vDst[cur ^ 1][1] = vn1;
    }
    // 4) one barrier per iter: publishes buf[cur^1], fences reads of buf[cur]
    __syncthreads();
  }

  // ---- 2-way kv merge per q-tile (pure adds; arena overlaid) ----
  const float lfull = crosshalf_sum(lp);
  float* mrow = mrg + (qsel * 32 + q) * 68;
  if (pr == 1) {
#pragma unroll
    for (int r2 = 0; r2 < 4; ++r2) {
      f32x4 s0, s1;
#pragma unroll
      for (int j = 0; j < 4; ++j) { s0[j] = o0[4 * r2 + j]; s1[j] = o1[4 * r2 + j]; }
      *(f32x4*)&mrow[8 * r2 + 4 * hi] = s0;
      *(f32x4*)&mrow[32 + 8 * r2 + 4 * hi] = s1;
    }
    if (hi == 0) lshp[qsel * 32 + q] = lfull;
  }
  __syncthreads();
  if (pr == 0) {
    const float inv = 1.f / (lfull + lshp[qsel * 32 + q]);
    float* orow = Ob + (size_t)(qr0 + q) * ROWSTRIDE;
#pragma unroll
    for (int r2 = 0; r2 < 4; ++r2) {
      const f32x4 pB0 = *(const f32x4*)&mrow[8 * r2 + 4 * hi];
      const f32x4 pB1 = *(const f32x4*)&mrow[32 + 8 * r2 + 4 * hi];
      f32x4 s0, s1;
#pragma unroll
      for (int j = 0; j < 4; ++j) {
        s0[j] = (o0[4 * r2 + j] + pB0[j]) * inv;
        s1[j] = (o1[4 * r2 + j] + pB1[j]) * inv;
      }
      *(f32x4*)(orow + 8 * r2 + 4 * hi) = s0;
      *(f32x4*)(orow + 32 + 8 * r2 + 4 * hi) = s1;
    }
  }
}

// ---------------------------------------------------------------------------
// Fallback if workspace too small (f32 direct; natural-exp domain)
// ---------------------------------------------------------------------------
__global__ __launch_bounds__(256, 4)
void mha_fwd_f32(const float* __restrict__ Qp, const float* __restrict__ Kp,
                 const float* __restrict__ Vp, float* __restrict__ Op) {
  const int bid = blockIdx.x;
  const int qt = 31 - (bid & 31);
  const int bh = bid >> 5;
  const int h = bh & 15;
  const int b = bh >> 4;
  const int tid = threadIdx.x;
  const int w = tid >> 6;
  const int lane = tid & 63;
  const int g = lane >> 4;
  const int c = lane & 15;

  __shared__ __align__(16) unsigned short Pb[4][16 * 64];
  unsigned short* P = Pb[w];

  const size_t base = (size_t)b * BSTRIDE + (size_t)h * D_;
  const float* Qb = Qp + base;
  const float* Kb = Kp + base;
  const float* Vb = Vp + base;
  float* Ob = Op + base;
  const int qr0 = qt * 64 + w * 16;

  bfrag8 qf[2];
  {
    const float* qp = Qb + (size_t)(qr0 + c) * ROWSTRIDE + g * 8;
#pragma unroll
    for (int s = 0; s < 2; ++s) {
      f32x4 a0 = *(const f32x4*)(qp + 32 * s);
      f32x4 a1 = *(const f32x4*)(qp + 32 * s + 4);
      bfrag8 f;
#pragma unroll
      for (int j = 0; j < 4; ++j) {
        f[j] = (short)f2bf(a0[j] * 0.125f);
        f[j + 4] = (short)f2bf(a1[j] * 0.125f);
      }
      qf[s] = f;
    }
  }
  float m_i[4], l_i[4];
  f32x4 oacc[4];
#pragma unroll
  for (int i = 0; i < 4; ++i) {
    m_i[i] = -INFINITY; l_i[i] = 0.f;
    oacc[i][0] = oacc[i][1] = oacc[i][2] = oacc[i][3] = 0.f;
  }
  for (int t = 0; t <= qt; ++t) {
    const int kv0 = t * 64;
    const bool diag = (t == qt);
    const int kbmax = diag ? w : 3;
    f32x4 sacc[4];
#pragma unroll
    for (int kb = 0; kb < 4; ++kb) {
      if (kb <= kbmax) {
        f32x4 acc; acc[0] = acc[1] = acc[2] = acc[3] = 0.f;
        const float* kp = Kb + (size_t)(kv0 + kb * 16 + c) * ROWSTRIDE + g * 8;
#pragma unroll
        for (int s = 0; s < 2; ++s) {
          f32x4 a0 = *(const f32x4*)(kp + 32 * s);
          f32x4 a1 = *(const f32x4*)(kp + 32 * s + 4);
          bfrag8 kf;
#pragma unroll
          for (int j = 0; j < 4; ++j) {
            kf[j] = (short)f2bf(a0[j]);
            kf[j + 4] = (short)f2bf(a1[j]);
          }
          acc = __builtin_amdgcn_mfma_f32_16x16x32_bf16(qf[s], kf, acc, 0, 0, 0);
        }
        if (diag && kb == w) {
#pragma unroll
          for (int i = 0; i < 4; ++i)
            if (c > 4 * g + i) acc[i] = -INFINITY;
        }
        sacc[kb] = acc;
      } else {
        sacc[kb][0] = sacc[kb][1] = sacc[kb][2] = sacc[kb][3] = -INFINITY;
      }
    }
    float tmax[4];
#pragma unroll
    for (int i = 0; i < 4; ++i)
      tmax[i] = fmaxf(fmaxf(sacc[0][i], sacc[1][i]), fmaxf(sacc[2][i], sacc[3][i]));
#pragma unroll
    for (int mk = 1; mk <= 8; mk <<= 1)
#pragma unroll
      for (int i = 0; i < 4; ++i) tmax[i] = fmaxf(tmax[i], __shfl_xor(tmax[i], mk));
    float rsum[4];
#pragma unroll
    for (int i = 0; i < 4; ++i) {
      const float mnew = fmaxf(m_i[i], tmax[i]);
      const float sc = __expf(m_i[i] - mnew);
      m_i[i] = mnew;
      float rs = 0.f;
#pragma unroll
      for (int kb = 0; kb < 4; ++kb) {
        const float p = __expf(sacc[kb][i] - mnew);
        sacc[kb][i] = p; rs += p;
      }
      rsum[i] = rs; l_i[i] *= sc;
#pragma unroll
      for (int db = 0; db < 4; ++db) oacc[db][i] *= sc;
    }
#pragma unroll
    for (int mk = 1; mk <= 8; mk <<= 1)
#pragma unroll
      for (int i = 0; i < 4; ++i) rsum[i] += __shfl_xor(rsum[i], mk);
#pragma unroll
    for (int i = 0; i < 4; ++i) l_i[i] += rsum[i];
#pragma unroll
    for (int kb = 0; kb < 4; ++kb) {
      const int col = kb * 16 + c;
      const int chunk = col >> 3;
      const int lo = col & 7;
#pragma unroll
      for (int i = 0; i < 4; ++i) {
        const int row = 4 * g + i;
        P[row * 64 + ((chunk ^ (row & 7)) * 8) + lo] = f2bf(sacc[kb][i]);
      }
    }
    asm volatile("s_waitcnt lgkmcnt(0)" ::: "memory");
    bfrag8 pa[2];
#pragma unroll
    for (int ks = 0; ks < 2; ++ks) {
      const int row = c;
      const int chunk = (4 * ks + g) ^ (row & 7);
      pa[ks] = *(const bfrag8*)&P[row * 64 + chunk * 8];
    }
#pragma unroll
    for (int ks = 0; ks < 2; ++ks) {
      const float* vp = Vb + (size_t)(kv0 + ks * 32 + g * 8) * ROWSTRIDE + c;
#pragma unroll
      for (int db = 0; db < 4; ++db) {
        bfrag8 vf;
#pragma unroll
        for (int j = 0; j < 8; ++j)
          vf[j] = (short)f2bf(vp[(size_t)j * ROWSTRIDE + db * 16]);
        oacc[db] = __builtin_amdgcn_mfma_f32_16x16x32_bf16(pa[ks], vf, oacc[db], 0, 0, 0);
      }
    }
  }
#pragma unroll
  for (int i = 0; i < 4; ++i) {
    const float inv = 1.f / l_i[i];
    const int qq = qr0 + 4 * g + i;
    float* op = Ob + (size_t)qq * ROWSTRIDE + c;
#pragma unroll
    for (int db = 0; db < 4; ++db)
      op[db * 16] = oacc[db][i] * inv;
  }
}

extern "C" void kernel_launch(void* const* d_in, const int* in_sizes, int n_in,
                              void* d_out, int out_size, void* d_ws, size_t ws_size,
                              hipStream_t stream) {
  const float* Q = (const float*)d_in[0];
  const float* K = (const float*)d_in[1];
  const float* V = (const float*)d_in[2];
  float* O = (float*)d_out;

  const size_t need = 3 * NTOT * sizeof(unsigned short);
  if (ws_size >= need) {
    unsigned short* Qb = (unsigned short*)d_ws;
    unsigned short* Kb = Qb + NTOT;
    unsigned short* Vt = Kb + NTOT;
    prep_kernel<<<dim3(2048), dim3(256), 0, stream>>>(Q, K, V, Qb, Kb, Vt);
    mha_fwd_db2<<<dim3(2048), dim3(256), 0, stream>>>(Qb, Kb, Vt, O);
  } else {
    mha_fwd_f32<<<dim3(2048), dim3(256), 0, stream>>>(Q, K, V, O);
  }
}

// Round 20
// 128.869 us; speedup vs baseline: 2.2572x; 2.2572x over previous
//
#include <hip/hip_runtime.h>
#include <hip/hip_bf16.h>

typedef __attribute__((ext_vector_type(8))) short bfrag8;           // 8 bf16
typedef __attribute__((ext_vector_type(8))) unsigned short u16x8;
typedef __attribute__((ext_vector_type(4))) float f32x4;
typedef __attribute__((ext_vector_type(16))) float f32x16;          // 32x32 MFMA C/D
typedef __attribute__((ext_vector_type(4))) unsigned int u32x4;

static constexpr int L_ = 2048;
static constexpr int H_ = 16;
static constexpr int D_ = 64;
static constexpr int ROWSTRIDE = H_ * D_;
static constexpr int BSTRIDE = L_ * H_ * D_;
static constexpr size_t NPH = (size_t)L_ * D_;
static constexpr size_t NTOT = (size_t)4 * H_ * L_ * D_;

// Finite "minus infinity" for masking (exp2(NEG - FIXM) == 0 exactly).
static constexpr float NEG = -1e30f;
// Fixed softmax reference max (exp2 domain); normalizer cancels in O = PV/l.
static constexpr float FIXM = 24.0f;

__device__ __forceinline__ unsigned short f2bf(float f) {
  return __builtin_bit_cast(unsigned short, __float2bfloat16(f));
}
__device__ __forceinline__ unsigned int pack2(float lo, float hi) {
  return (unsigned int)f2bf(lo) | ((unsigned int)f2bf(hi) << 16);
}

// Cross-half (lane i <-> i+32) sum via permlane32_swap builtin (verified r6).
__device__ __forceinline__ float crosshalf_sum(float x) {
  const unsigned xu = __builtin_bit_cast(unsigned int, x);
  auto r = __builtin_amdgcn_permlane32_swap(xu, xu, false, false);
  return __builtin_bit_cast(float, (unsigned int)r[0]) +
         __builtin_bit_cast(float, (unsigned int)r[1]);
}

// ---------------------------------------------------------------------------
// Prep: f32 [B,L,H,D] -> bf16 Qb[B,H,L,D] (x 0.125*log2e), Kb[B,H,L,D],
// Vt[B,H,D,L].  Scores then live in exp2 domain.
// ---------------------------------------------------------------------------
__global__ __launch_bounds__(256, 4)
void prep_kernel(const float* __restrict__ Q, const float* __restrict__ K,
                 const float* __restrict__ V, unsigned short* __restrict__ Qb,
                 unsigned short* __restrict__ Kb, unsigned short* __restrict__ Vt) {
  const int bid = blockIdx.x;
  const int lt = bid & 31;
  const int bh = bid >> 5;
  const int h = bh & 15;
  const int b = bh >> 4;
  const int l0 = lt * 64;
  const int t = threadIdx.x;
  const int lr = t >> 2;
  const int dc = t & 3;

  __shared__ __align__(16) unsigned short vt[64 * 64];

  const size_t src = ((size_t)(b * L_ + l0 + lr) * H_ + h) * D_ + dc * 16;
  const size_t dst = ((size_t)bh * L_ + l0 + lr) * D_ + dc * 16;

  constexpr float QS = 0.125f * 1.44269504088896341f;   // (1/sqrt(D)) * log2(e)

  {
    f32x4 a = *(const f32x4*)(Q + src),     b4 = *(const f32x4*)(Q + src + 4),
          c4 = *(const f32x4*)(Q + src + 8), d4 = *(const f32x4*)(Q + src + 12);
    u16x8 o0, o1;
#pragma unroll
    for (int j = 0; j < 4; ++j) {
      o0[j] = f2bf(a[j] * QS);  o0[j + 4] = f2bf(b4[j] * QS);
      o1[j] = f2bf(c4[j] * QS); o1[j + 4] = f2bf(d4[j] * QS);
    }
    *(u16x8*)(Qb + dst) = o0;
    *(u16x8*)(Qb + dst + 8) = o1;
  }
  {
    f32x4 a = *(const f32x4*)(K + src),     b4 = *(const f32x4*)(K + src + 4),
          c4 = *(const f32x4*)(K + src + 8), d4 = *(const f32x4*)(K + src + 12);
    u16x8 o0, o1;
#pragma unroll
    for (int j = 0; j < 4; ++j) {
      o0[j] = f2bf(a[j]);  o0[j + 4] = f2bf(b4[j]);
      o1[j] = f2bf(c4[j]); o1[j + 4] = f2bf(d4[j]);
    }
    *(u16x8*)(Kb + dst) = o0;
    *(u16x8*)(Kb + dst + 8) = o1;
  }
  {
    f32x4 a = *(const f32x4*)(V + src),     b4 = *(const f32x4*)(V + src + 4),
          c4 = *(const f32x4*)(V + src + 8), d4 = *(const f32x4*)(V + src + 12);
    u16x8 o0, o1;
#pragma unroll
    for (int j = 0; j < 4; ++j) {
      o0[j] = f2bf(a[j]);  o0[j + 4] = f2bf(b4[j]);
      o1[j] = f2bf(c4[j]); o1[j + 4] = f2bf(d4[j]);
    }
    const int r7 = (lr + (lr >> 3)) & 7;
    *(u16x8*)&vt[lr * 64 + (((dc * 2) ^ r7) * 8)] = o0;
    *(u16x8*)&vt[lr * 64 + (((dc * 2 + 1) ^ r7) * 8)] = o1;
  }
  __syncthreads();
  {
    const int d = t >> 2;
    const int lc = t & 3;
    const int ch = d >> 3, dl = d & 7;
    u16x8 o0, o1;
#pragma unroll
    for (int i = 0; i < 8; ++i) {
      const int r0 = lc * 16 + i;
      const int r1 = lc * 16 + 8 + i;
      o0[i] = vt[r0 * 64 + ((ch ^ ((r0 + (r0 >> 3)) & 7)) * 8) + dl];
      o1[i] = vt[r1 * 64 + ((ch ^ ((r1 + (r1 >> 3)) & 7)) * 8) + dl];
    }
    const size_t vd = ((size_t)bh * D_ + d) * L_ + l0 + lc * 16;
    *(u16x8*)(Vt + vd) = o0;
    *(u16x8*)(Vt + vd + 8) = o1;
  }
}

// ---------------------------------------------------------------------------
// Pair-block staged-LDS flash attention (r19 concept, scratch bug fixed).
// r19 ERRATUM: local POINTER ARRAYS (kDst[2][2], kMy[2]) indexed by runtime
// `cur` went to scratch (rule #20 pointer form): FETCH 527MB, 3.6x slower.
// Fix: ALL LDS addresses computed arithmetically (arena + expr*4096 + off).
// Structure: block = 2 adjacent q-tiles {2p,2p+1}; 4 waves = q-tile x
// kv-parity -> every wave computes every iteration. Each iteration stages a
// PAIR of kv-tiles into the alternate 16KB half of a 32KB double buffer
// (issue-early global->regs, compute, write-late, ONE barrier = r15 schedule).
// 32KB/block -> 4 blocks/CU LDS cap; grid 2048 = 2x capacity -> backfill
// queue sustains occupancy. Longest-first. 2-way kv merge = pure adds.
// launch_bounds(256,4): VGPR 64. NEVER tighten the cap (r17: 14x slower).
// ---------------------------------------------------------------------------
__global__ __launch_bounds__(256, 4)
void mha_fwd_db2(const unsigned short* __restrict__ Qb,
                 const unsigned short* __restrict__ Kb,
                 const unsigned short* __restrict__ Vt,
                 float* __restrict__ Op) {
  const int bid = blockIdx.x;
  const int plane = bid & 63;               // b*16 + h
  const int p = 31 - (bid >> 6);            // q-tile pair index, longest first
  const int h = plane & 15;
  const int b = plane >> 4;

  const int tid = threadIdx.x;
  const int wv = tid >> 6;
  const int qsel = wv >> 1;                 // 0 -> qt=2p, 1 -> qt=2p+1
  const int pr = wv & 1;                    // kv-tile parity for this wave
  const int lane = tid & 63;
  const int q = lane & 31;
  const int hi = lane >> 5;

  const int qt = 2 * p + qsel;
  const int qr0 = qt * 32;
  const int P = p + 1;                      // iterations (2 kv-tiles each)

  // 32KB double-buffered pair staging; K slab [buf*2+tile]*4096, V at +16384.
  // Merge overlays the arena after the final barrier.
  __shared__ __align__(16) unsigned char arena[32768];
  float* mrg = (float*)arena;                          // [2][32][68] f32
  float* lshp = (float*)(arena + 17408);               // [2][32] f32

  const unsigned short* Qh = Qb + (size_t)plane * NPH;
  const unsigned short* Kh = Kb + (size_t)plane * NPH;
  const unsigned short* Vh = Vt + (size_t)plane * NPH;
  float* Ob = Op + (size_t)b * BSTRIDE + (size_t)h * D_;

  // staging roles (fixed per thread), XOR-chunk swizzle (write == read)
  const int kr = tid >> 3, kc = tid & 7;    // K: row 0..31, 16B chunk 0..7
  const int vr = tid >> 2, vc = tid & 3;    // V^T: row 0..63, 16B chunk 0..3
  const int kOff = kr * 64 + ((kc ^ (kr & 7)) * 8);   // elements
  const int vOff = vr * 32 + ((vc ^ (vr & 3)) * 8);

  // Q B-frags: lane holds Q[qr0+q][16s + 8hi + j]
  bfrag8 qB[4];
#pragma unroll
  for (int s = 0; s < 4; ++s)
    qB[s] = *(const bfrag8*)(Qh + (qr0 + q) * D_ + 16 * s + 8 * hi);

  float lp = 0.f;
  f32x16 o0 = {};                            // O[q][d = crow + 0..31]
  f32x16 o1 = {};                            // O[q][d = crow + 32..63]

  // prologue: stage pair 0 (tiles 0,1) into buf 0 (arithmetic addresses)
  {
    u16x8 k0 = *(const u16x8*)(Kh + (size_t)kr * D_ + kc * 8);
    u16x8 v0 = *(const u16x8*)(Vh + (size_t)vr * L_ + vc * 8);
    u16x8 k1 = *(const u16x8*)(Kh + (size_t)(32 + kr) * D_ + kc * 8);
    u16x8 v1 = *(const u16x8*)(Vh + (size_t)vr * L_ + 32 + vc * 8);
    *(u16x8*)((unsigned short*)(arena) + kOff) = k0;
    *(u16x8*)((unsigned short*)(arena + 4096) + kOff) = k1;
    *(u16x8*)((unsigned short*)(arena + 16384) + vOff) = v0;
    *(u16x8*)((unsigned short*)(arena + 16384 + 4096) + vOff) = v1;
  }
  __syncthreads();

  for (int k = 0; k < P; ++k) {
    const int cur = k & 1;
    const int t = 2 * k + pr;                // my kv-tile this iteration
    const bool more = (k + 1 < P);

    // 1) issue next pair's global loads (land during compute below)
    u16x8 kn0, vn0, kn1, vn1;
    if (more) {
      const int base = (k + 1) * 64;         // rows of tile 2k+2
      kn0 = *(const u16x8*)(Kh + (size_t)(base + kr) * D_ + kc * 8);
      vn0 = *(const u16x8*)(Vh + (size_t)vr * L_ + base + vc * 8);
      kn1 = *(const u16x8*)(Kh + (size_t)(base + 32 + kr) * D_ + kc * 8);
      vn1 = *(const u16x8*)(Vh + (size_t)vr * L_ + base + 32 + vc * 8);
    }

    // 2) compute my tile (guard false only for wave (qsel0,pr1) at k=p)
    if (t <= qt) {
      // arithmetic LDS bases: slab index = cur*2 + pr (runtime, pure math)
      const unsigned short* kb =
          (const unsigned short*)(arena + (size_t)(cur * 2 + pr) * 4096);
      const unsigned short* vb =
          (const unsigned short*)(arena + 16384 + (size_t)(cur * 2 + pr) * 4096);
      bfrag8 kA[4];
#pragma unroll
      for (int s = 0; s < 4; ++s)
        kA[s] = *(const bfrag8*)&kb[q * 64 + (((2 * s + hi) ^ (q & 7)) * 8)];
      bfrag8 vA[2][2];
#pragma unroll
      for (int ks = 0; ks < 2; ++ks)
#pragma unroll
        for (int dh = 0; dh < 2; ++dh)
          vA[ks][dh] = *(const bfrag8*)&vb[(32 * dh + q) * 32 + (((2 * ks + hi) ^ (q & 3)) * 8)];

      f32x16 sacc = {};
      __builtin_amdgcn_s_setprio(1);
#pragma unroll
      for (int s = 0; s < 4; ++s)
        sacc = __builtin_amdgcn_mfma_f32_32x32x16_bf16(kA[s], qB[s], sacc, 0, 0, 0);
      __builtin_amdgcn_s_setprio(0);

      if (t == qt) {
#pragma unroll
        for (int r = 0; r < 16; ++r) {
          const int crow = (r & 3) + 8 * (r >> 2) + 4 * hi;
          if (crow > q) sacc[r] = NEG;
        }
      }

#pragma unroll
      for (int r = 0; r < 16; ++r) sacc[r] = __builtin_exp2f(sacc[r] - FIXM);
      {
        float s8[8];
#pragma unroll
        for (int r = 0; r < 8; ++r) s8[r] = sacc[2 * r] + sacc[2 * r + 1];
#pragma unroll
        for (int r = 0; r < 4; ++r) s8[r] += s8[r + 4];
        lp += (s8[0] + s8[2]) + (s8[1] + s8[3]);
      }

      const unsigned int a0 = pack2(sacc[0],  sacc[1]),  a1 = pack2(sacc[2],  sacc[3]);
      const unsigned int a2 = pack2(sacc[4],  sacc[5]),  a3 = pack2(sacc[6],  sacc[7]);
      const unsigned int a4 = pack2(sacc[8],  sacc[9]),  a5 = pack2(sacc[10], sacc[11]);
      const unsigned int a6 = pack2(sacc[12], sacc[13]), a7 = pack2(sacc[14], sacc[15]);
      auto r02 = __builtin_amdgcn_permlane32_swap(a0, a2, false, false);
      auto r13 = __builtin_amdgcn_permlane32_swap(a1, a3, false, false);
      auto r46 = __builtin_amdgcn_permlane32_swap(a4, a6, false, false);
      auto r57 = __builtin_amdgcn_permlane32_swap(a5, a7, false, false);
      u32x4 w0, w1;
      w0[0] = r02[0]; w0[1] = r13[0]; w0[2] = r02[1]; w0[3] = r13[1];
      w1[0] = r46[0]; w1[1] = r57[0]; w1[2] = r46[1]; w1[3] = r57[1];
      const bfrag8 pb0 = __builtin_bit_cast(bfrag8, w0);
      const bfrag8 pb1 = __builtin_bit_cast(bfrag8, w1);

      __builtin_amdgcn_s_setprio(1);
      o0 = __builtin_amdgcn_mfma_f32_32x32x16_bf16(vA[0][0], pb0, o0, 0, 0, 0);
      o0 = __builtin_amdgcn_mfma_f32_32x32x16_bf16(vA[1][0], pb1, o0, 0, 0, 0);
      o1 = __builtin_amdgcn_mfma_f32_32x32x16_bf16(vA[0][1], pb0, o1, 0, 0, 0);
      o1 = __builtin_amdgcn_mfma_f32_32x32x16_bf16(vA[1][1], pb1, o1, 0, 0, 0);
      __builtin_amdgcn_s_setprio(0);
    }

    // 3) write-late into the OTHER buffer (arithmetic addresses, no arrays)
    if (more) {
      unsigned char* kslab = arena + (size_t)((cur ^ 1) * 2) * 4096;
      unsigned char* vslab = arena + 16384 + (size_t)((cur ^ 1) * 2) * 4096;
      *(u16x8*)((unsigned short*)kslab + kOff) = kn0;
      *(u16x8*)((unsigned short*)(kslab + 4096) + kOff) = kn1;
      *(u16x8*)((unsigned short*)vslab + vOff) = vn0;
      *(u16x8*)((unsigned short*)(vslab + 4096) + vOff) = vn1;
    }
    // 4) one barrier per iter: publishes buf[cur^1], fences reads of buf[cur]
    __syncthreads();
  }

  // ---- 2-way kv merge per q-tile (pure adds; arena overlaid) ----
  const float lfull = crosshalf_sum(lp);
  float* mrow = mrg + (qsel * 32 + q) * 68;
  if (pr == 1) {
#pragma unroll
    for (int r2 = 0; r2 < 4; ++r2) {
      f32x4 s0, s1;
#pragma unroll
      for (int j = 0; j < 4; ++j) { s0[j] = o0[4 * r2 + j]; s1[j] = o1[4 * r2 + j]; }
      *(f32x4*)&mrow[8 * r2 + 4 * hi] = s0;
      *(f32x4*)&mrow[32 + 8 * r2 + 4 * hi] = s1;
    }
    if (hi == 0) lshp[qsel * 32 + q] = lfull;
  }
  __syncthreads();
  if (pr == 0) {
    const float inv = 1.f / (lfull + lshp[qsel * 32 + q]);
    float* orow = Ob + (size_t)(qr0 + q) * ROWSTRIDE;
#pragma unroll
    for (int r2 = 0; r2 < 4; ++r2) {
      const f32x4 pB0 = *(const f32x4*)&mrow[8 * r2 + 4 * hi];
      const f32x4 pB1 = *(const f32x4*)&mrow[32 + 8 * r2 + 4 * hi];
      f32x4 s0, s1;
#pragma unroll
      for (int j = 0; j < 4; ++j) {
        s0[j] = (o0[4 * r2 + j] + pB0[j]) * inv;
        s1[j] = (o1[4 * r2 + j] + pB1[j]) * inv;
      }
      *(f32x4*)(orow + 8 * r2 + 4 * hi) = s0;
      *(f32x4*)(orow + 32 + 8 * r2 + 4 * hi) = s1;
    }
  }
}

// ---------------------------------------------------------------------------
// Fallback if workspace too small (f32 direct; natural-exp domain)
// ---------------------------------------------------------------------------
__global__ __launch_bounds__(256, 4)
void mha_fwd_f32(const float* __restrict__ Qp, const float* __restrict__ Kp,
                 const float* __restrict__ Vp, float* __restrict__ Op) {
  const int bid = blockIdx.x;
  const int qt = 31 - (bid & 31);
  const int bh = bid >> 5;
  const int h = bh & 15;
  const int b = bh >> 4;
  const int tid = threadIdx.x;
  const int w = tid >> 6;
  const int lane = tid & 63;
  const int g = lane >> 4;
  const int c = lane & 15;

  __shared__ __align__(16) unsigned short Pb[4][16 * 64];
  unsigned short* P = Pb[w];

  const size_t base = (size_t)b * BSTRIDE + (size_t)h * D_;
  const float* Qb = Qp + base;
  const float* Kb = Kp + base;
  const float* Vb = Vp + base;
  float* Ob = Op + base;
  const int qr0 = qt * 64 + w * 16;

  bfrag8 qf[2];
  {
    const float* qp = Qb + (size_t)(qr0 + c) * ROWSTRIDE + g * 8;
#pragma unroll
    for (int s = 0; s < 2; ++s) {
      f32x4 a0 = *(const f32x4*)(qp + 32 * s);
      f32x4 a1 = *(const f32x4*)(qp + 32 * s + 4);
      bfrag8 f;
#pragma unroll
      for (int j = 0; j < 4; ++j) {
        f[j] = (short)f2bf(a0[j] * 0.125f);
        f[j + 4] = (short)f2bf(a1[j] * 0.125f);
      }
      qf[s] = f;
    }
  }
  float m_i[4], l_i[4];
  f32x4 oacc[4];
#pragma unroll
  for (int i = 0; i < 4; ++i) {
    m_i[i] = -INFINITY; l_i[i] = 0.f;
    oacc[i][0] = oacc[i][1] = oacc[i][2] = oacc[i][3] = 0.f;
  }
  for (int t = 0; t <= qt; ++t) {
    const int kv0 = t * 64;
    const bool diag = (t == qt);
    const int kbmax = diag ? w : 3;
    f32x4 sacc[4];
#pragma unroll
    for (int kb = 0; kb < 4; ++kb) {
      if (kb <= kbmax) {
        f32x4 acc; acc[0] = acc[1] = acc[2] = acc[3] = 0.f;
        const float* kp = Kb + (size_t)(kv0 + kb * 16 + c) * ROWSTRIDE + g * 8;
#pragma unroll
        for (int s = 0; s < 2; ++s) {
          f32x4 a0 = *(const f32x4*)(kp + 32 * s);
          f32x4 a1 = *(const f32x4*)(kp + 32 * s + 4);
          bfrag8 kf;
#pragma unroll
          for (int j = 0; j < 4; ++j) {
            kf[j] = (short)f2bf(a0[j]);
            kf[j + 4] = (short)f2bf(a1[j]);
          }
          acc = __builtin_amdgcn_mfma_f32_16x16x32_bf16(qf[s], kf, acc, 0, 0, 0);
        }
        if (diag && kb == w) {
#pragma unroll
          for (int i = 0; i < 4; ++i)
            if (c > 4 * g + i) acc[i] = -INFINITY;
        }
        sacc[kb] = acc;
      } else {
        sacc[kb][0] = sacc[kb][1] = sacc[kb][2] = sacc[kb][3] = -INFINITY;
      }
    }
    float tmax[4];
#pragma unroll
    for (int i = 0; i < 4; ++i)
      tmax[i] = fmaxf(fmaxf(sacc[0][i], sacc[1][i]), fmaxf(sacc[2][i], sacc[3][i]));
#pragma unroll
    for (int mk = 1; mk <= 8; mk <<= 1)
#pragma unroll
      for (int i = 0; i < 4; ++i) tmax[i] = fmaxf(tmax[i], __shfl_xor(tmax[i], mk));
    float rsum[4];
#pragma unroll
    for (int i = 0; i < 4; ++i) {
      const float mnew = fmaxf(m_i[i], tmax[i]);
      const float sc = __expf(m_i[i] - mnew);
      m_i[i] = mnew;
      float rs = 0.f;
#pragma unroll
      for (int kb = 0; kb < 4; ++kb) {
        const float p = __expf(sacc[kb][i] - mnew);
        sacc[kb][i] = p; rs += p;
      }
      rsum[i] = rs; l_i[i] *= sc;
#pragma unroll
      for (int db = 0; db < 4; ++db) oacc[db][i] *= sc;
    }
#pragma unroll
    for (int mk = 1; mk <= 8; mk <<= 1)
#pragma unroll
      for (int i = 0; i < 4; ++i) rsum[i] += __shfl_xor(rsum[i], mk);
#pragma unroll
    for (int i = 0; i < 4; ++i) l_i[i] += rsum[i];
#pragma unroll
    for (int kb = 0; kb < 4; ++kb) {
      const int col = kb * 16 + c;
      const int chunk = col >> 3;
      const int lo = col & 7;
#pragma unroll
      for (int i = 0; i < 4; ++i) {
        const int row = 4 * g + i;
        P[row * 64 + ((chunk ^ (row & 7)) * 8) + lo] = f2bf(sacc[kb][i]);
      }
    }
    asm volatile("s_waitcnt lgkmcnt(0)" ::: "memory");
    bfrag8 pa[2];
#pragma unroll
    for (int ks = 0; ks < 2; ++ks) {
      const int row = c;
      const int chunk = (4 * ks + g) ^ (row & 7);
      pa[ks] = *(const bfrag8*)&P[row * 64 + chunk * 8];
    }
#pragma unroll
    for (int ks = 0; ks < 2; ++ks) {
      const float* vp = Vb + (size_t)(kv0 + ks * 32 + g * 8) * ROWSTRIDE + c;
#pragma unroll
      for (int db = 0; db < 4; ++db) {
        bfrag8 vf;
#pragma unroll
        for (int j = 0; j < 8; ++j)
          vf[j] = (short)f2bf(vp[(size_t)j * ROWSTRIDE + db * 16]);
        oacc[db] = __builtin_amdgcn_mfma_f32_16x16x32_bf16(pa[ks], vf, oacc[db], 0, 0, 0);
      }
    }
  }
#pragma unroll
  for (int i = 0; i < 4; ++i) {
    const float inv = 1.f / l_i[i];
    const int qq = qr0 + 4 * g + i;
    float* op = Ob + (size_t)qq * ROWSTRIDE + c;
#pragma unroll
    for (int db = 0; db < 4; ++db)
      op[db * 16] = oacc[db][i] * inv;
  }
}

extern "C" void kernel_launch(void* const* d_in, const int* in_sizes, int n_in,
                              void* d_out, int out_size, void* d_ws, size_t ws_size,
                              hipStream_t stream) {
  const float* Q = (const float*)d_in[0];
  const float* K = (const float*)d_in[1];
  const float* V = (const float*)d_in[2];
  float* O = (float*)d_out;

  const size_t need = 3 * NTOT * sizeof(unsigned short);
  if (ws_size >= need) {
    unsigned short* Qb = (unsigned short*)d_ws;
    unsigned short* Kb = Qb + NTOT;
    unsigned short* Vt = Kb + NTOT;
    prep_kernel<<<dim3(2048), dim3(256), 0, stream>>>(Q, K, V, Qb, Kb, Vt);
    mha_fwd_db2<<<dim3(2048), dim3(256), 0, stream>>>(Qb, Kb, Vt, O);
  } else {
    mha_fwd_f32<<<dim3(2048), dim3(256), 0, stream>>>(Q, K, V, O);
  }
}

// Round 21
// 94.666 us; speedup vs baseline: 3.0727x; 1.3613x over previous
//
#include <hip/hip_runtime.h>
#include <hip/hip_bf16.h>

typedef __attribute__((ext_vector_type(8))) short bfrag8;           // 8 bf16
typedef __attribute__((ext_vector_type(8))) unsigned short u16x8;
typedef __attribute__((ext_vector_type(4))) float f32x4;
typedef __attribute__((ext_vector_type(16))) float f32x16;          // 32x32 MFMA C/D
typedef __attribute__((ext_vector_type(4))) unsigned int u32x4;

static constexpr int L_ = 2048;
static constexpr int H_ = 16;
static constexpr int D_ = 64;
static constexpr int ROWSTRIDE = H_ * D_;
static constexpr int BSTRIDE = L_ * H_ * D_;
static constexpr size_t NPH = (size_t)L_ * D_;
static constexpr size_t NTOT = (size_t)4 * H_ * L_ * D_;

// Finite "minus infinity" for masking (exp2(NEG - FIXM) == 0 exactly).
static constexpr float NEG = -1e30f;
// Fixed softmax reference max (exp2 domain); normalizer cancels in O = PV/l.
static constexpr float FIXM = 24.0f;

__device__ __forceinline__ unsigned short f2bf(float f) {
  return __builtin_bit_cast(unsigned short, __float2bfloat16(f));
}
__device__ __forceinline__ unsigned int pack2(float lo, float hi) {
  return (unsigned int)f2bf(lo) | ((unsigned int)f2bf(hi) << 16);
}

// Cross-half (lane i <-> i+32) sum via permlane32_swap builtin (verified r6).
__device__ __forceinline__ float crosshalf_sum(float x) {
  const unsigned xu = __builtin_bit_cast(unsigned int, x);
  auto r = __builtin_amdgcn_permlane32_swap(xu, xu, false, false);
  return __builtin_bit_cast(float, (unsigned int)r[0]) +
         __builtin_bit_cast(float, (unsigned int)r[1]);
}

// ---------------------------------------------------------------------------
// Prep: f32 [B,L,H,D] -> bf16 Qb[B,H,L,D] (x 0.125*log2e), Kb[B,H,L,D],
// Vt[B,H,D,L].  Scores then live in exp2 domain.
// ---------------------------------------------------------------------------
__global__ __launch_bounds__(256, 4)
void prep_kernel(const float* __restrict__ Q, const float* __restrict__ K,
                 const float* __restrict__ V, unsigned short* __restrict__ Qb,
                 unsigned short* __restrict__ Kb, unsigned short* __restrict__ Vt) {
  const int bid = blockIdx.x;
  const int lt = bid & 31;
  const int bh = bid >> 5;
  const int h = bh & 15;
  const int b = bh >> 4;
  const int l0 = lt * 64;
  const int t = threadIdx.x;
  const int lr = t >> 2;
  const int dc = t & 3;

  __shared__ __align__(16) unsigned short vt[64 * 64];

  const size_t src = ((size_t)(b * L_ + l0 + lr) * H_ + h) * D_ + dc * 16;
  const size_t dst = ((size_t)bh * L_ + l0 + lr) * D_ + dc * 16;

  constexpr float QS = 0.125f * 1.44269504088896341f;   // (1/sqrt(D)) * log2(e)

  {
    f32x4 a = *(const f32x4*)(Q + src),     b4 = *(const f32x4*)(Q + src + 4),
          c4 = *(const f32x4*)(Q + src + 8), d4 = *(const f32x4*)(Q + src + 12);
    u16x8 o0, o1;
#pragma unroll
    for (int j = 0; j < 4; ++j) {
      o0[j] = f2bf(a[j] * QS);  o0[j + 4] = f2bf(b4[j] * QS);
      o1[j] = f2bf(c4[j] * QS); o1[j + 4] = f2bf(d4[j] * QS);
    }
    *(u16x8*)(Qb + dst) = o0;
    *(u16x8*)(Qb + dst + 8) = o1;
  }
  {
    f32x4 a = *(const f32x4*)(K + src),     b4 = *(const f32x4*)(K + src + 4),
          c4 = *(const f32x4*)(K + src + 8), d4 = *(const f32x4*)(K + src + 12);
    u16x8 o0, o1;
#pragma unroll
    for (int j = 0; j < 4; ++j) {
      o0[j] = f2bf(a[j]);  o0[j + 4] = f2bf(b4[j]);
      o1[j] = f2bf(c4[j]); o1[j + 4] = f2bf(d4[j]);
    }
    *(u16x8*)(Kb + dst) = o0;
    *(u16x8*)(Kb + dst + 8) = o1;
  }
  {
    f32x4 a = *(const f32x4*)(V + src),     b4 = *(const f32x4*)(V + src + 4),
          c4 = *(const f32x4*)(V + src + 8), d4 = *(const f32x4*)(V + src + 12);
    u16x8 o0, o1;
#pragma unroll
    for (int j = 0; j < 4; ++j) {
      o0[j] = f2bf(a[j]);  o0[j + 4] = f2bf(b4[j]);
      o1[j] = f2bf(c4[j]); o1[j + 4] = f2bf(d4[j]);
    }
    const int r7 = (lr + (lr >> 3)) & 7;
    *(u16x8*)&vt[lr * 64 + (((dc * 2) ^ r7) * 8)] = o0;
    *(u16x8*)&vt[lr * 64 + (((dc * 2 + 1) ^ r7) * 8)] = o1;
  }
  __syncthreads();
  {
    const int d = t >> 2;
    const int lc = t & 3;
    const int ch = d >> 3, dl = d & 7;
    u16x8 o0, o1;
#pragma unroll
    for (int i = 0; i < 8; ++i) {
      const int r0 = lc * 16 + i;
      const int r1 = lc * 16 + 8 + i;
      o0[i] = vt[r0 * 64 + ((ch ^ ((r0 + (r0 >> 3)) & 7)) * 8) + dl];
      o1[i] = vt[r1 * 64 + ((ch ^ ((r1 + (r1 >> 3)) & 7)) * 8) + dl];
    }
    const size_t vd = ((size_t)bh * D_ + d) * L_ + l0 + lc * 16;
    *(u16x8*)(Vt + vd) = o0;
    *(u16x8*)(Vt + vd + 8) = o1;
  }
}

// ---------------------------------------------------------------------------
// Pair-block staged-LDS flash attention (r20 + MID-BODY staged-reg release).
// r20's residual spill (WRITE +32MB, SGPR 112): the 4 staged u16x8 (32 VGPR)
// stayed live across the whole compute body -> peak live set > the 64-reg
// equilibrium the allocator targets. Fix: ds_write the staged regs right
// after the QK MFMA (loads have had QK-duration to land; regs die BEFORE
// softmax/PV; V-frag LDS reads deferred until after the release).
// Structure (r20): block = 2 adjacent q-tiles {2p,2p+1}; 4 waves = q-tile x
// kv-parity; pair of kv-tiles staged per iter into alternate 16KB half of a
// 32KB double buffer; ONE barrier/iter; grid 2048 (backfill); longest-first;
// 2-way kv merge = pure adds. All LDS addresses arithmetic (r19 erratum).
// launch_bounds(256,4): VGPR 64. NEVER tighten the cap (r17: 14x slower).
// ---------------------------------------------------------------------------
__global__ __launch_bounds__(256, 4)
void mha_fwd_db2(const unsigned short* __restrict__ Qb,
                 const unsigned short* __restrict__ Kb,
                 const unsigned short* __restrict__ Vt,
                 float* __restrict__ Op) {
  const int bid = blockIdx.x;
  const int plane = bid & 63;               // b*16 + h
  const int p = 31 - (bid >> 6);            // q-tile pair index, longest first
  const int h = plane & 15;
  const int b = plane >> 4;

  const int tid = threadIdx.x;
  const int wv = tid >> 6;
  const int qsel = wv >> 1;                 // 0 -> qt=2p, 1 -> qt=2p+1
  const int pr = wv & 1;                    // kv-tile parity for this wave
  const int lane = tid & 63;
  const int q = lane & 31;
  const int hi = lane >> 5;

  const int qt = 2 * p + qsel;
  const int qr0 = qt * 32;
  const int P = p + 1;                      // iterations (2 kv-tiles each)

  // 32KB double-buffered pair staging; K slab [buf*2+tile]*4096, V at +16384.
  __shared__ __align__(16) unsigned char arena[32768];
  float* mrg = (float*)arena;                          // [2][32][68] f32
  float* lshp = (float*)(arena + 17408);               // [2][32] f32

  const unsigned short* Qh = Qb + (size_t)plane * NPH;
  const unsigned short* Kh = Kb + (size_t)plane * NPH;
  const unsigned short* Vh = Vt + (size_t)plane * NPH;
  float* Ob = Op + (size_t)b * BSTRIDE + (size_t)h * D_;

  // staging roles (fixed per thread), XOR-chunk swizzle (write == read)
  const int kr = tid >> 3, kc = tid & 7;    // K: row 0..31, 16B chunk 0..7
  const int vr = tid >> 2, vc = tid & 3;    // V^T: row 0..63, 16B chunk 0..3
  const int kOff = kr * 64 + ((kc ^ (kr & 7)) * 8);   // elements
  const int vOff = vr * 32 + ((vc ^ (vr & 3)) * 8);

  // Q B-frags: lane holds Q[qr0+q][16s + 8hi + j]
  bfrag8 qB[4];
#pragma unroll
  for (int s = 0; s < 4; ++s)
    qB[s] = *(const bfrag8*)(Qh + (qr0 + q) * D_ + 16 * s + 8 * hi);

  float lp = 0.f;
  f32x16 o0 = {};                            // O[q][d = crow + 0..31]
  f32x16 o1 = {};                            // O[q][d = crow + 32..63]

  // prologue: stage pair 0 (tiles 0,1) into buf 0 (arithmetic addresses)
  {
    u16x8 k0 = *(const u16x8*)(Kh + (size_t)kr * D_ + kc * 8);
    u16x8 v0 = *(const u16x8*)(Vh + (size_t)vr * L_ + vc * 8);
    u16x8 k1 = *(const u16x8*)(Kh + (size_t)(32 + kr) * D_ + kc * 8);
    u16x8 v1 = *(const u16x8*)(Vh + (size_t)vr * L_ + 32 + vc * 8);
    *(u16x8*)((unsigned short*)(arena) + kOff) = k0;
    *(u16x8*)((unsigned short*)(arena + 4096) + kOff) = k1;
    *(u16x8*)((unsigned short*)(arena + 16384) + vOff) = v0;
    *(u16x8*)((unsigned short*)(arena + 16384 + 4096) + vOff) = v1;
  }
  __syncthreads();

  for (int k = 0; k < P; ++k) {
    const int cur = k & 1;
    const int t = 2 * k + pr;                // my kv-tile this iteration
    const bool more = (k + 1 < P);
    const bool docomp = (t <= qt);

    // 1) issue next pair's global loads
    u16x8 kn0, vn0, kn1, vn1;
    if (more) {
      const int base = (k + 1) * 64;         // rows of tile 2k+2
      kn0 = *(const u16x8*)(Kh + (size_t)(base + kr) * D_ + kc * 8);
      vn0 = *(const u16x8*)(Vh + (size_t)vr * L_ + base + vc * 8);
      kn1 = *(const u16x8*)(Kh + (size_t)(base + 32 + kr) * D_ + kc * 8);
      vn1 = *(const u16x8*)(Vh + (size_t)vr * L_ + base + 32 + vc * 8);
    }

    // 2) QK MFMA (loads land underneath; V-frag reads deferred)
    f32x16 sacc = {};
    if (docomp) {
      const unsigned short* kb =
          (const unsigned short*)(arena + (size_t)(cur * 2 + pr) * 4096);
      bfrag8 kA[4];
#pragma unroll
      for (int s = 0; s < 4; ++s)
        kA[s] = *(const bfrag8*)&kb[q * 64 + (((2 * s + hi) ^ (q & 7)) * 8)];
      __builtin_amdgcn_s_setprio(1);
#pragma unroll
      for (int s = 0; s < 4; ++s)
        sacc = __builtin_amdgcn_mfma_f32_32x32x16_bf16(kA[s], qB[s], sacc, 0, 0, 0);
      __builtin_amdgcn_s_setprio(0);
    }

    // 3) RELEASE staged regs: write into the other buffer NOW (regs die here,
    //    before softmax/PV; target buffer's readers finished last iteration)
    if (more) {
      unsigned char* kslab = arena + (size_t)((cur ^ 1) * 2) * 4096;
      unsigned char* vslab = arena + 16384 + (size_t)((cur ^ 1) * 2) * 4096;
      *(u16x8*)((unsigned short*)kslab + kOff) = kn0;
      *(u16x8*)((unsigned short*)(kslab + 4096) + kOff) = kn1;
      *(u16x8*)((unsigned short*)vslab + vOff) = vn0;
      *(u16x8*)((unsigned short*)(vslab + 4096) + vOff) = vn1;
    }

    // 4) softmax + PV (V-frags read here, after the release)
    if (docomp) {
      if (t == qt) {
#pragma unroll
        for (int r = 0; r < 16; ++r) {
          const int crow = (r & 3) + 8 * (r >> 2) + 4 * hi;
          if (crow > q) sacc[r] = NEG;
        }
      }

#pragma unroll
      for (int r = 0; r < 16; ++r) sacc[r] = __builtin_exp2f(sacc[r] - FIXM);
      {
        float s8[8];
#pragma unroll
        for (int r = 0; r < 8; ++r) s8[r] = sacc[2 * r] + sacc[2 * r + 1];
#pragma unroll
        for (int r = 0; r < 4; ++r) s8[r] += s8[r + 4];
        lp += (s8[0] + s8[2]) + (s8[1] + s8[3]);
      }

      const unsigned int a0 = pack2(sacc[0],  sacc[1]),  a1 = pack2(sacc[2],  sacc[3]);
      const unsigned int a2 = pack2(sacc[4],  sacc[5]),  a3 = pack2(sacc[6],  sacc[7]);
      const unsigned int a4 = pack2(sacc[8],  sacc[9]),  a5 = pack2(sacc[10], sacc[11]);
      const unsigned int a6 = pack2(sacc[12], sacc[13]), a7 = pack2(sacc[14], sacc[15]);
      auto r02 = __builtin_amdgcn_permlane32_swap(a0, a2, false, false);
      auto r13 = __builtin_amdgcn_permlane32_swap(a1, a3, false, false);
      auto r46 = __builtin_amdgcn_permlane32_swap(a4, a6, false, false);
      auto r57 = __builtin_amdgcn_permlane32_swap(a5, a7, false, false);
      u32x4 w0, w1;
      w0[0] = r02[0]; w0[1] = r13[0]; w0[2] = r02[1]; w0[3] = r13[1];
      w1[0] = r46[0]; w1[1] = r57[0]; w1[2] = r46[1]; w1[3] = r57[1];
      const bfrag8 pb0 = __builtin_bit_cast(bfrag8, w0);
      const bfrag8 pb1 = __builtin_bit_cast(bfrag8, w1);

      const unsigned short* vb =
          (const unsigned short*)(arena + 16384 + (size_t)(cur * 2 + pr) * 4096);
      bfrag8 vA[2][2];
#pragma unroll
      for (int ks = 0; ks < 2; ++ks)
#pragma unroll
        for (int dh = 0; dh < 2; ++dh)
          vA[ks][dh] = *(const bfrag8*)&vb[(32 * dh + q) * 32 + (((2 * ks + hi) ^ (q & 3)) * 8)];

      __builtin_amdgcn_s_setprio(1);
      o0 = __builtin_amdgcn_mfma_f32_32x32x16_bf16(vA[0][0], pb0, o0, 0, 0, 0);
      o0 = __builtin_amdgcn_mfma_f32_32x32x16_bf16(vA[1][0], pb1, o0, 0, 0, 0);
      o1 = __builtin_amdgcn_mfma_f32_32x32x16_bf16(vA[0][1], pb0, o1, 0, 0, 0);
      o1 = __builtin_amdgcn_mfma_f32_32x32x16_bf16(vA[1][1], pb1, o1, 0, 0, 0);
      __builtin_amdgcn_s_setprio(0);
    }

    // 5) one barrier per iter: publishes buf[cur^1], fences reads of buf[cur]
    __syncthreads();
  }

  // ---- 2-way kv merge per q-tile (pure adds; arena overlaid) ----
  const float lfull = crosshalf_sum(lp);
  float* mrow = mrg + (qsel * 32 + q) * 68;
  if (pr == 1) {
#pragma unroll
    for (int r2 = 0; r2 < 4; ++r2) {
      f32x4 s0, s1;
#pragma unroll
      for (int j = 0; j < 4; ++j) { s0[j] = o0[4 * r2 + j]; s1[j] = o1[4 * r2 + j]; }
      *(f32x4*)&mrow[8 * r2 + 4 * hi] = s0;
      *(f32x4*)&mrow[32 + 8 * r2 + 4 * hi] = s1;
    }
    if (hi == 0) lshp[qsel * 32 + q] = lfull;
  }
  __syncthreads();
  if (pr == 0) {
    const float inv = 1.f / (lfull + lshp[qsel * 32 + q]);
    float* orow = Ob + (size_t)(qr0 + q) * ROWSTRIDE;
#pragma unroll
    for (int r2 = 0; r2 < 4; ++r2) {
      const f32x4 pB0 = *(const f32x4*)&mrow[8 * r2 + 4 * hi];
      const f32x4 pB1 = *(const f32x4*)&mrow[32 + 8 * r2 + 4 * hi];
      f32x4 s0, s1;
#pragma unroll
      for (int j = 0; j < 4; ++j) {
        s0[j] = (o0[4 * r2 + j] + pB0[j]) * inv;
        s1[j] = (o1[4 * r2 + j] + pB1[j]) * inv;
      }
      *(f32x4*)(orow + 8 * r2 + 4 * hi) = s0;
      *(f32x4*)(orow + 32 + 8 * r2 + 4 * hi) = s1;
    }
  }
}

// ---------------------------------------------------------------------------
// Fallback if workspace too small (f32 direct; natural-exp domain)
// ---------------------------------------------------------------------------
__global__ __launch_bounds__(256, 4)
void mha_fwd_f32(const float* __restrict__ Qp, const float* __restrict__ Kp,
                 const float* __restrict__ Vp, float* __restrict__ Op) {
  const int bid = blockIdx.x;
  const int qt = 31 - (bid & 31);
  const int bh = bid >> 5;
  const int h = bh & 15;
  const int b = bh >> 4;
  const int tid = threadIdx.x;
  const int w = tid >> 6;
  const int lane = tid & 63;
  const int g = lane >> 4;
  const int c = lane & 15;

  __shared__ __align__(16) unsigned short Pb[4][16 * 64];
  unsigned short* P = Pb[w];

  const size_t base = (size_t)b * BSTRIDE + (size_t)h * D_;
  const float* Qb = Qp + base;
  const float* Kb = Kp + base;
  const float* Vb = Vp + base;
  float* Ob = Op + base;
  const int qr0 = qt * 64 + w * 16;

  bfrag8 qf[2];
  {
    const float* qp = Qb + (size_t)(qr0 + c) * ROWSTRIDE + g * 8;
#pragma unroll
    for (int s = 0; s < 2; ++s) {
      f32x4 a0 = *(const f32x4*)(qp + 32 * s);
      f32x4 a1 = *(const f32x4*)(qp + 32 * s + 4);
      bfrag8 f;
#pragma unroll
      for (int j = 0; j < 4; ++j) {
        f[j] = (short)f2bf(a0[j] * 0.125f);
        f[j + 4] = (short)f2bf(a1[j] * 0.125f);
      }
      qf[s] = f;
    }
  }
  float m_i[4], l_i[4];
  f32x4 oacc[4];
#pragma unroll
  for (int i = 0; i < 4; ++i) {
    m_i[i] = -INFINITY; l_i[i] = 0.f;
    oacc[i][0] = oacc[i][1] = oacc[i][2] = oacc[i][3] = 0.f;
  }
  for (int t = 0; t <= qt; ++t) {
    const int kv0 = t * 64;
    const bool diag = (t == qt);
    const int kbmax = diag ? w : 3;
    f32x4 sacc[4];
#pragma unroll
    for (int kb = 0; kb < 4; ++kb) {
      if (kb <= kbmax) {
        f32x4 acc; acc[0] = acc[1] = acc[2] = acc[3] = 0.f;
        const float* kp = Kb + (size_t)(kv0 + kb * 16 + c) * ROWSTRIDE + g * 8;
#pragma unroll
        for (int s = 0; s < 2; ++s) {
          f32x4 a0 = *(const f32x4*)(kp + 32 * s);
          f32x4 a1 = *(const f32x4*)(kp + 32 * s + 4);
          bfrag8 kf;
#pragma unroll
          for (int j = 0; j < 4; ++j) {
            kf[j] = (short)f2bf(a0[j]);
            kf[j + 4] = (short)f2bf(a1[j]);
          }
          acc = __builtin_amdgcn_mfma_f32_16x16x32_bf16(qf[s], kf, acc, 0, 0, 0);
        }
        if (diag && kb == w) {
#pragma unroll
          for (int i = 0; i < 4; ++i)
            if (c > 4 * g + i) acc[i] = -INFINITY;
        }
        sacc[kb] = acc;
      } else {
        sacc[kb][0] = sacc[kb][1] = sacc[kb][2] = sacc[kb][3] = -INFINITY;
      }
    }
    float tmax[4];
#pragma unroll
    for (int i = 0; i < 4; ++i)
      tmax[i] = fmaxf(fmaxf(sacc[0][i], sacc[1][i]), fmaxf(sacc[2][i], sacc[3][i]));
#pragma unroll
    for (int mk = 1; mk <= 8; mk <<= 1)
#pragma unroll
      for (int i = 0; i < 4; ++i) tmax[i] = fmaxf(tmax[i], __shfl_xor(tmax[i], mk));
    float rsum[4];
#pragma unroll
    for (int i = 0; i < 4; ++i) {
      const float mnew = fmaxf(m_i[i], tmax[i]);
      const float sc = __expf(m_i[i] - mnew);
      m_i[i] = mnew;
      float rs = 0.f;
#pragma unroll
      for (int kb = 0; kb < 4; ++kb) {
        const float p = __expf(sacc[kb][i] - mnew);
        sacc[kb][i] = p; rs += p;
      }
      rsum[i] = rs; l_i[i] *= sc;
#pragma unroll
      for (int db = 0; db < 4; ++db) oacc[db][i] *= sc;
    }
#pragma unroll
    for (int mk = 1; mk <= 8; mk <<= 1)
#pragma unroll
      for (int i = 0; i < 4; ++i) rsum[i] += __shfl_xor(rsum[i], mk);
#pragma unroll
    for (int i = 0; i < 4; ++i) l_i[i] += rsum[i];
#pragma unroll
    for (int kb = 0; kb < 4; ++kb) {
      const int col = kb * 16 + c;
      const int chunk = col >> 3;
      const int lo = col & 7;
#pragma unroll
      for (int i = 0; i < 4; ++i) {
        const int row = 4 * g + i;
        P[row * 64 + ((chunk ^ (row & 7)) * 8) + lo] = f2bf(sacc[kb][i]);
      }
    }
    asm volatile("s_waitcnt lgkmcnt(0)" ::: "memory");
    bfrag8 pa[2];
#pragma unroll
    for (int ks = 0; ks < 2; ++ks) {
      const int row = c;
      const int chunk = (4 * ks + g) ^ (row & 7);
      pa[ks] = *(const bfrag8*)&P[row * 64 + chunk * 8];
    }
#pragma unroll
    for (int ks = 0; ks < 2; ++ks) {
      const float* vp = Vb + (size_t)(kv0 + ks * 32 + g * 8) * ROWSTRIDE + c;
#pragma unroll
      for (int db = 0; db < 4; ++db) {
        bfrag8 vf;
#pragma unroll
        for (int j = 0; j < 8; ++j)
          vf[j] = (short)f2bf(vp[(size_t)j * ROWSTRIDE + db * 16]);
        oacc[db] = __builtin_amdgcn_mfma_f32_16x16x32_bf16(pa[ks], vf, oacc[db], 0, 0, 0);
      }
    }
  }
#pragma unroll
  for (int i = 0; i < 4; ++i) {
    const float inv = 1.f / l_i[i];
    const int qq = qr0 + 4 * g + i;
    float* op = Ob + (size_t)qq * ROWSTRIDE + c;
#pragma unroll
    for (int db = 0; db < 4; ++db)
      op[db * 16] = oacc[db][i] * inv;
  }
}

extern "C" void kernel_launch(void* const* d_in, const int* in_sizes, int n_in,
                              void* d_out, int out_size, void* d_ws, size_t ws_size,
                              hipStream_t stream) {
  const float* Q = (const float*)d_in[0];
  const float* K = (const float*)d_in[1];
  const float* V = (const float*)d_in[2];
  float* O = (float*)d_out;

  const size_t need = 3 * NTOT * sizeof(unsigned short);
  if (ws_size >= need) {
    unsigned short* Qb = (unsigned short*)d_ws;
    unsigned short* Kb = Qb + NTOT;
    unsigned short* Vt = Kb + NTOT;
    prep_kernel<<<dim3(2048), dim3(256), 0, stream>>>(Q, K, V, Qb, Kb, Vt);
    mha_fwd_db2<<<dim3(2048), dim3(256), 0, stream>>>(Qb, Kb, Vt, O);
  } else {
    mha_fwd_f32<<<dim3(2048), dim3(256), 0, stream>>>(Q, K, V, O);
  }
}

// Round 22
// 88.846 us; speedup vs baseline: 3.2740x; 1.0655x over previous
//
#include <hip/hip_runtime.h>
#include <hip/hip_bf16.h>

typedef __attribute__((ext_vector_type(8))) short bfrag8;           // 8 bf16
typedef __attribute__((ext_vector_type(8))) unsigned short u16x8;
typedef __attribute__((ext_vector_type(4))) float f32x4;
typedef __attribute__((ext_vector_type(16))) float f32x16;          // 32x32 MFMA C/D
typedef __attribute__((ext_vector_type(4))) unsigned int u32x4;

static constexpr int L_ = 2048;
static constexpr int H_ = 16;
static constexpr int D_ = 64;
static constexpr int ROWSTRIDE = H_ * D_;
static constexpr int BSTRIDE = L_ * H_ * D_;
static constexpr size_t NPH = (size_t)L_ * D_;
static constexpr size_t NTOT = (size_t)4 * H_ * L_ * D_;

// Finite "minus infinity" for masking (exp2(NEG - FIXM) == 0 exactly).
static constexpr float NEG = -1e30f;
// Fixed softmax reference max (exp2 domain); normalizer cancels in O = PV/l.
static constexpr float FIXM = 24.0f;
// (1/sqrt(D)) * log2(e): folded into Q at load time -> scores in exp2 domain.
static constexpr float QS = 0.125f * 1.44269504088896341f;

__device__ __forceinline__ unsigned short f2bf(float f) {
  return __builtin_bit_cast(unsigned short, __float2bfloat16(f));
}
__device__ __forceinline__ unsigned int pack2(float lo, float hi) {
  return (unsigned int)f2bf(lo) | ((unsigned int)f2bf(hi) << 16);
}

// Cross-half (lane i <-> i+32) sum via permlane32_swap builtin (verified r6).
__device__ __forceinline__ float crosshalf_sum(float x) {
  const unsigned xu = __builtin_bit_cast(unsigned int, x);
  auto r = __builtin_amdgcn_permlane32_swap(xu, xu, false, false);
  return __builtin_bit_cast(float, (unsigned int)r[0]) +
         __builtin_bit_cast(float, (unsigned int)r[1]);
}

// ---------------------------------------------------------------------------
// Prep: f32 [B,L,H,D] -> bf16 Kb[B,H,L,D], Vt[B,H,D,L].
// Q is NOT prepped (r22): attention reads f32 Q directly (each Q element is
// consumed exactly once, so the bf16 round-trip was pure wasted traffic:
// -56MB prep traffic for +19MB attn reads).
// ---------------------------------------------------------------------------
__global__ __launch_bounds__(256, 4)
void prep_kernel(const float* __restrict__ K, const float* __restrict__ V,
                 unsigned short* __restrict__ Kb, unsigned short* __restrict__ Vt) {
  const int bid = blockIdx.x;
  const int lt = bid & 31;
  const int bh = bid >> 5;
  const int h = bh & 15;
  const int b = bh >> 4;
  const int l0 = lt * 64;
  const int t = threadIdx.x;
  const int lr = t >> 2;
  const int dc = t & 3;

  __shared__ __align__(16) unsigned short vt[64 * 64];

  const size_t src = ((size_t)(b * L_ + l0 + lr) * H_ + h) * D_ + dc * 16;
  const size_t dst = ((size_t)bh * L_ + l0 + lr) * D_ + dc * 16;

  {
    f32x4 a = *(const f32x4*)(K + src),     b4 = *(const f32x4*)(K + src + 4),
          c4 = *(const f32x4*)(K + src + 8), d4 = *(const f32x4*)(K + src + 12);
    u16x8 o0, o1;
#pragma unroll
    for (int j = 0; j < 4; ++j) {
      o0[j] = f2bf(a[j]);  o0[j + 4] = f2bf(b4[j]);
      o1[j] = f2bf(c4[j]); o1[j + 4] = f2bf(d4[j]);
    }
    *(u16x8*)(Kb + dst) = o0;
    *(u16x8*)(Kb + dst + 8) = o1;
  }
  {
    f32x4 a = *(const f32x4*)(V + src),     b4 = *(const f32x4*)(V + src + 4),
          c4 = *(const f32x4*)(V + src + 8), d4 = *(const f32x4*)(V + src + 12);
    u16x8 o0, o1;
#pragma unroll
    for (int j = 0; j < 4; ++j) {
      o0[j] = f2bf(a[j]);  o0[j + 4] = f2bf(b4[j]);
      o1[j] = f2bf(c4[j]); o1[j + 4] = f2bf(d4[j]);
    }
    const int r7 = (lr + (lr >> 3)) & 7;
    *(u16x8*)&vt[lr * 64 + (((dc * 2) ^ r7) * 8)] = o0;
    *(u16x8*)&vt[lr * 64 + (((dc * 2 + 1) ^ r7) * 8)] = o1;
  }
  __syncthreads();
  {
    const int d = t >> 2;
    const int lc = t & 3;
    const int ch = d >> 3, dl = d & 7;
    u16x8 o0, o1;
#pragma unroll
    for (int i = 0; i < 8; ++i) {
      const int r0 = lc * 16 + i;
      const int r1 = lc * 16 + 8 + i;
      o0[i] = vt[r0 * 64 + ((ch ^ ((r0 + (r0 >> 3)) & 7)) * 8) + dl];
      o1[i] = vt[r1 * 64 + ((ch ^ ((r1 + (r1 >> 3)) & 7)) * 8) + dl];
    }
    const size_t vd = ((size_t)bh * D_ + d) * L_ + l0 + lc * 16;
    *(u16x8*)(Vt + vd) = o0;
    *(u16x8*)(Vt + vd + 8) = o1;
  }
}

// ---------------------------------------------------------------------------
// Pair-block staged-LDS flash attention (r21 structure, Q read as f32 direct).
// r21 verified: mid-body staged-reg release -> no spill, 78us, VALUBusy 72%.
// This round only changes the Q PROLOGUE (f32 gather + in-reg cvt+scale, 16
// loads once per wave) and deletes Q from prep. Hot loop byte-identical.
// Structure: block = 2 adjacent q-tiles {2p,2p+1}; 4 waves = q-tile x
// kv-parity; pair of kv-tiles staged per iter into alternate 16KB half of a
// 32KB double buffer; issue-early -> QK -> release staged regs (die before
// softmax) -> softmax+PV -> ONE barrier. Grid 2048 (backfill), longest-first,
// 2-way kv merge = pure adds. All LDS addresses arithmetic (r19 erratum).
// launch_bounds(256,4): VGPR 64. NEVER tighten the cap (r17: 14x slower).
// ---------------------------------------------------------------------------
__global__ __launch_bounds__(256, 4)
void mha_fwd_db2(const float* __restrict__ Qf,
                 const unsigned short* __restrict__ Kb,
                 const unsigned short* __restrict__ Vt,
                 float* __restrict__ Op) {
  const int bid = blockIdx.x;
  const int plane = bid & 63;               // b*16 + h
  const int p = 31 - (bid >> 6);            // q-tile pair index, longest first
  const int h = plane & 15;
  const int b = plane >> 4;

  const int tid = threadIdx.x;
  const int wv = tid >> 6;
  const int qsel = wv >> 1;                 // 0 -> qt=2p, 1 -> qt=2p+1
  const int pr = wv & 1;                    // kv-tile parity for this wave
  const int lane = tid & 63;
  const int q = lane & 31;
  const int hi = lane >> 5;

  const int qt = 2 * p + qsel;
  const int qr0 = qt * 32;
  const int P = p + 1;                      // iterations (2 kv-tiles each)

  // 32KB double-buffered pair staging; K slab [buf*2+tile]*4096, V at +16384.
  __shared__ __align__(16) unsigned char arena[32768];
  float* mrg = (float*)arena;                          // [2][32][68] f32
  float* lshp = (float*)(arena + 17408);               // [2][32] f32

  const unsigned short* Kh = Kb + (size_t)plane * NPH;
  const unsigned short* Vh = Vt + (size_t)plane * NPH;
  float* Ob = Op + (size_t)b * BSTRIDE + (size_t)h * D_;

  // staging roles (fixed per thread), XOR-chunk swizzle (write == read)
  const int kr = tid >> 3, kc = tid & 7;    // K: row 0..31, 16B chunk 0..7
  const int vr = tid >> 2, vc = tid & 3;    // V^T: row 0..63, 16B chunk 0..3
  const int kOff = kr * 64 + ((kc ^ (kr & 7)) * 8);   // elements
  const int vOff = vr * 32 + ((vc ^ (vr & 3)) * 8);

  // Q B-frags from f32 source (once per wave; scale+log2e folded in).
  // lane holds Q[qr0+q][16s + 8hi + j], j=0..7
  bfrag8 qB[4];
  {
    const float* qrow = Qf + ((size_t)(b * L_ + qr0 + q)) * ROWSTRIDE + h * D_;
#pragma unroll
    for (int s = 0; s < 4; ++s) {
      const f32x4 lo = *(const f32x4*)(qrow + 16 * s + 8 * hi);
      const f32x4 hi4 = *(const f32x4*)(qrow + 16 * s + 8 * hi + 4);
      bfrag8 f;
#pragma unroll
      for (int j = 0; j < 4; ++j) {
        f[j]     = (short)f2bf(lo[j] * QS);
        f[j + 4] = (short)f2bf(hi4[j] * QS);
      }
      qB[s] = f;
    }
  }

  float lp = 0.f;
  f32x16 o0 = {};                            // O[q][d = crow + 0..31]
  f32x16 o1 = {};                            // O[q][d = crow + 32..63]

  // prologue: stage pair 0 (tiles 0,1) into buf 0 (arithmetic addresses)
  {
    u16x8 k0 = *(const u16x8*)(Kh + (size_t)kr * D_ + kc * 8);
    u16x8 v0 = *(const u16x8*)(Vh + (size_t)vr * L_ + vc * 8);
    u16x8 k1 = *(const u16x8*)(Kh + (size_t)(32 + kr) * D_ + kc * 8);
    u16x8 v1 = *(const u16x8*)(Vh + (size_t)vr * L_ + 32 + vc * 8);
    *(u16x8*)((unsigned short*)(arena) + kOff) = k0;
    *(u16x8*)((unsigned short*)(arena + 4096) + kOff) = k1;
    *(u16x8*)((unsigned short*)(arena + 16384) + vOff) = v0;
    *(u16x8*)((unsigned short*)(arena + 16384 + 4096) + vOff) = v1;
  }
  __syncthreads();

  for (int k = 0; k < P; ++k) {
    const int cur = k & 1;
    const int t = 2 * k + pr;                // my kv-tile this iteration
    const bool more = (k + 1 < P);
    const bool docomp = (t <= qt);

    // 1) issue next pair's global loads
    u16x8 kn0, vn0, kn1, vn1;
    if (more) {
      const int base = (k + 1) * 64;         // rows of tile 2k+2
      kn0 = *(const u16x8*)(Kh + (size_t)(base + kr) * D_ + kc * 8);
      vn0 = *(const u16x8*)(Vh + (size_t)vr * L_ + base + vc * 8);
      kn1 = *(const u16x8*)(Kh + (size_t)(base + 32 + kr) * D_ + kc * 8);
      vn1 = *(const u16x8*)(Vh + (size_t)vr * L_ + base + 32 + vc * 8);
    }

    // 2) QK MFMA (loads land underneath; V-frag reads deferred)
    f32x16 sacc = {};
    if (docomp) {
      const unsigned short* kb =
          (const unsigned short*)(arena + (size_t)(cur * 2 + pr) * 4096);
      bfrag8 kA[4];
#pragma unroll
      for (int s = 0; s < 4; ++s)
        kA[s] = *(const bfrag8*)&kb[q * 64 + (((2 * s + hi) ^ (q & 7)) * 8)];
      __builtin_amdgcn_s_setprio(1);
#pragma unroll
      for (int s = 0; s < 4; ++s)
        sacc = __builtin_amdgcn_mfma_f32_32x32x16_bf16(kA[s], qB[s], sacc, 0, 0, 0);
      __builtin_amdgcn_s_setprio(0);
    }

    // 3) RELEASE staged regs: write into the other buffer NOW (regs die here,
    //    before softmax/PV; target buffer's readers finished last iteration)
    if (more) {
      unsigned char* kslab = arena + (size_t)((cur ^ 1) * 2) * 4096;
      unsigned char* vslab = arena + 16384 + (size_t)((cur ^ 1) * 2) * 4096;
      *(u16x8*)((unsigned short*)kslab + kOff) = kn0;
      *(u16x8*)((unsigned short*)(kslab + 4096) + kOff) = kn1;
      *(u16x8*)((unsigned short*)vslab + vOff) = vn0;
      *(u16x8*)((unsigned short*)(vslab + 4096) + vOff) = vn1;
    }

    // 4) softmax + PV (V-frags read here, after the release)
    if (docomp) {
      if (t == qt) {
#pragma unroll
        for (int r = 0; r < 16; ++r) {
          const int crow = (r & 3) + 8 * (r >> 2) + 4 * hi;
          if (crow > q) sacc[r] = NEG;
        }
      }

#pragma unroll
      for (int r = 0; r < 16; ++r) sacc[r] = __builtin_exp2f(sacc[r] - FIXM);
      {
        float s8[8];
#pragma unroll
        for (int r = 0; r < 8; ++r) s8[r] = sacc[2 * r] + sacc[2 * r + 1];
#pragma unroll
        for (int r = 0; r < 4; ++r) s8[r] += s8[r + 4];
        lp += (s8[0] + s8[2]) + (s8[1] + s8[3]);
      }

      const unsigned int a0 = pack2(sacc[0],  sacc[1]),  a1 = pack2(sacc[2],  sacc[3]);
      const unsigned int a2 = pack2(sacc[4],  sacc[5]),  a3 = pack2(sacc[6],  sacc[7]);
      const unsigned int a4 = pack2(sacc[8],  sacc[9]),  a5 = pack2(sacc[10], sacc[11]);
      const unsigned int a6 = pack2(sacc[12], sacc[13]), a7 = pack2(sacc[14], sacc[15]);
      auto r02 = __builtin_amdgcn_permlane32_swap(a0, a2, false, false);
      auto r13 = __builtin_amdgcn_permlane32_swap(a1, a3, false, false);
      auto r46 = __builtin_amdgcn_permlane32_swap(a4, a6, false, false);
      auto r57 = __builtin_amdgcn_permlane32_swap(a5, a7, false, false);
      u32x4 w0, w1;
      w0[0] = r02[0]; w0[1] = r13[0]; w0[2] = r02[1]; w0[3] = r13[1];
      w1[0] = r46[0]; w1[1] = r57[0]; w1[2] = r46[1]; w1[3] = r57[1];
      const bfrag8 pb0 = __builtin_bit_cast(bfrag8, w0);
      const bfrag8 pb1 = __builtin_bit_cast(bfrag8, w1);

      const unsigned short* vb =
          (const unsigned short*)(arena + 16384 + (size_t)(cur * 2 + pr) * 4096);
      bfrag8 vA[2][2];
#pragma unroll
      for (int ks = 0; ks < 2; ++ks)
#pragma unroll
        for (int dh = 0; dh < 2; ++dh)
          vA[ks][dh] = *(const bfrag8*)&vb[(32 * dh + q) * 32 + (((2 * ks + hi) ^ (q & 3)) * 8)];

      __builtin_amdgcn_s_setprio(1);
      o0 = __builtin_amdgcn_mfma_f32_32x32x16_bf16(vA[0][0], pb0, o0, 0, 0, 0);
      o0 = __builtin_amdgcn_mfma_f32_32x32x16_bf16(vA[1][0], pb1, o0, 0, 0, 0);
      o1 = __builtin_amdgcn_mfma_f32_32x32x16_bf16(vA[0][1], pb0, o1, 0, 0, 0);
      o1 = __builtin_amdgcn_mfma_f32_32x32x16_bf16(vA[1][1], pb1, o1, 0, 0, 0);
      __builtin_amdgcn_s_setprio(0);
    }

    // 5) one barrier per iter: publishes buf[cur^1], fences reads of buf[cur]
    __syncthreads();
  }

  // ---- 2-way kv merge per q-tile (pure adds; arena overlaid) ----
  const float lfull = crosshalf_sum(lp);
  float* mrow = mrg + (qsel * 32 + q) * 68;
  if (pr == 1) {
#pragma unroll
    for (int r2 = 0; r2 < 4; ++r2) {
      f32x4 s0, s1;
#pragma unroll
      for (int j = 0; j < 4; ++j) { s0[j] = o0[4 * r2 + j]; s1[j] = o1[4 * r2 + j]; }
      *(f32x4*)&mrow[8 * r2 + 4 * hi] = s0;
      *(f32x4*)&mrow[32 + 8 * r2 + 4 * hi] = s1;
    }
    if (hi == 0) lshp[qsel * 32 + q] = lfull;
  }
  __syncthreads();
  if (pr == 0) {
    const float inv = 1.f / (lfull + lshp[qsel * 32 + q]);
    float* orow = Ob + (size_t)(qr0 + q) * ROWSTRIDE;
#pragma unroll
    for (int r2 = 0; r2 < 4; ++r2) {
      const f32x4 pB0 = *(const f32x4*)&mrow[8 * r2 + 4 * hi];
      const f32x4 pB1 = *(const f32x4*)&mrow[32 + 8 * r2 + 4 * hi];
      f32x4 s0, s1;
#pragma unroll
      for (int j = 0; j < 4; ++j) {
        s0[j] = (o0[4 * r2 + j] + pB0[j]) * inv;
        s1[j] = (o1[4 * r2 + j] + pB1[j]) * inv;
      }
      *(f32x4*)(orow + 8 * r2 + 4 * hi) = s0;
      *(f32x4*)(orow + 32 + 8 * r2 + 4 * hi) = s1;
    }
  }
}

// ---------------------------------------------------------------------------
// Fallback if workspace too small (f32 direct; natural-exp domain)
// ---------------------------------------------------------------------------
__global__ __launch_bounds__(256, 4)
void mha_fwd_f32(const float* __restrict__ Qp, const float* __restrict__ Kp,
                 const float* __restrict__ Vp, float* __restrict__ Op) {
  const int bid = blockIdx.x;
  const int qt = 31 - (bid & 31);
  const int bh = bid >> 5;
  const int h = bh & 15;
  const int b = bh >> 4;
  const int tid = threadIdx.x;
  const int w = tid >> 6;
  const int lane = tid & 63;
  const int g = lane >> 4;
  const int c = lane & 15;

  __shared__ __align__(16) unsigned short Pb[4][16 * 64];
  unsigned short* P = Pb[w];

  const size_t base = (size_t)b * BSTRIDE + (size_t)h * D_;
  const float* Qb = Qp + base;
  const float* Kb = Kp + base;
  const float* Vb = Vp + base;
  float* Ob = Op + base;
  const int qr0 = qt * 64 + w * 16;

  bfrag8 qf[2];
  {
    const float* qp = Qb + (size_t)(qr0 + c) * ROWSTRIDE + g * 8;
#pragma unroll
    for (int s = 0; s < 2; ++s) {
      f32x4 a0 = *(const f32x4*)(qp + 32 * s);
      f32x4 a1 = *(const f32x4*)(qp + 32 * s + 4);
      bfrag8 f;
#pragma unroll
      for (int j = 0; j < 4; ++j) {
        f[j] = (short)f2bf(a0[j] * 0.125f);
        f[j + 4] = (short)f2bf(a1[j] * 0.125f);
      }
      qf[s] = f;
    }
  }
  float m_i[4], l_i[4];
  f32x4 oacc[4];
#pragma unroll
  for (int i = 0; i < 4; ++i) {
    m_i[i] = -INFINITY; l_i[i] = 0.f;
    oacc[i][0] = oacc[i][1] = oacc[i][2] = oacc[i][3] = 0.f;
  }
  for (int t = 0; t <= qt; ++t) {
    const int kv0 = t * 64;
    const bool diag = (t == qt);
    const int kbmax = diag ? w : 3;
    f32x4 sacc[4];
#pragma unroll
    for (int kb = 0; kb < 4; ++kb) {
      if (kb <= kbmax) {
        f32x4 acc; acc[0] = acc[1] = acc[2] = acc[3] = 0.f;
        const float* kp = Kb + (size_t)(kv0 + kb * 16 + c) * ROWSTRIDE + g * 8;
#pragma unroll
        for (int s = 0; s < 2; ++s) {
          f32x4 a0 = *(const f32x4*)(kp + 32 * s);
          f32x4 a1 = *(const f32x4*)(kp + 32 * s + 4);
          bfrag8 kf;
#pragma unroll
          for (int j = 0; j < 4; ++j) {
            kf[j] = (short)f2bf(a0[j]);
            kf[j + 4] = (short)f2bf(a1[j]);
          }
          acc = __builtin_amdgcn_mfma_f32_16x16x32_bf16(qf[s], kf, acc, 0, 0, 0);
        }
        if (diag && kb == w) {
#pragma unroll
          for (int i = 0; i < 4; ++i)
            if (c > 4 * g + i) acc[i] = -INFINITY;
        }
        sacc[kb] = acc;
      } else {
        sacc[kb][0] = sacc[kb][1] = sacc[kb][2] = sacc[kb][3] = -INFINITY;
      }
    }
    float tmax[4];
#pragma unroll
    for (int i = 0; i < 4; ++i)
      tmax[i] = fmaxf(fmaxf(sacc[0][i], sacc[1][i]), fmaxf(sacc[2][i], sacc[3][i]));
#pragma unroll
    for (int mk = 1; mk <= 8; mk <<= 1)
#pragma unroll
      for (int i = 0; i < 4; ++i) tmax[i] = fmaxf(tmax[i], __shfl_xor(tmax[i], mk));
    float rsum[4];
#pragma unroll
    for (int i = 0; i < 4; ++i) {
      const float mnew = fmaxf(m_i[i], tmax[i]);
      const float sc = __expf(m_i[i] - mnew);
      m_i[i] = mnew;
      float rs = 0.f;
#pragma unroll
      for (int kb = 0; kb < 4; ++kb) {
        const float p = __expf(sacc[kb][i] - mnew);
        sacc[kb][i] = p; rs += p;
      }
      rsum[i] = rs; l_i[i] *= sc;
#pragma unroll
      for (int db = 0; db < 4; ++db) oacc[db][i] *= sc;
    }
#pragma unroll
    for (int mk = 1; mk <= 8; mk <<= 1)
#pragma unroll
      for (int i = 0; i < 4; ++i) rsum[i] += __shfl_xor(rsum[i], mk);
#pragma unroll
    for (int i = 0; i < 4; ++i) l_i[i] += rsum[i];
#pragma unroll
    for (int kb = 0; kb < 4; ++kb) {
      const int col = kb * 16 + c;
      const int chunk = col >> 3;
      const int lo = col & 7;
#pragma unroll
      for (int i = 0; i < 4; ++i) {
        const int row = 4 * g + i;
        P[row * 64 + ((chunk ^ (row & 7)) * 8) + lo] = f2bf(sacc[kb][i]);
      }
    }
    asm volatile("s_waitcnt lgkmcnt(0)" ::: "memory");
    bfrag8 pa[2];
#pragma unroll
    for (int ks = 0; ks < 2; ++ks) {
      const int row = c;
      const int chunk = (4 * ks + g) ^ (row & 7);
      pa[ks] = *(const bfrag8*)&P[row * 64 + chunk * 8];
    }
#pragma unroll
    for (int ks = 0; ks < 2; ++ks) {
      const float* vp = Vb + (size_t)(kv0 + ks * 32 + g * 8) * ROWSTRIDE + c;
#pragma unroll
      for (int db = 0; db < 4; ++db) {
        bfrag8 vf;
#pragma unroll
        for (int j = 0; j < 8; ++j)
          vf[j] = (short)f2bf(vp[(size_t)j * ROWSTRIDE + db * 16]);
        oacc[db] = __builtin_amdgcn_mfma_f32_16x16x32_bf16(pa[ks], vf, oacc[db], 0, 0, 0);
      }
    }
  }
#pragma unroll
  for (int i = 0; i < 4; ++i) {
    const float inv = 1.f / l_i[i];
    const int qq = qr0 + 4 * g + i;
    float* op = Ob + (size_t)qq * ROWSTRIDE + c;
#pragma unroll
    for (int db = 0; db < 4; ++db)
      op[db * 16] = oacc[db][i] * inv;
  }
}

extern "C" void kernel_launch(void* const* d_in, const int* in_sizes, int n_in,
                              void* d_out, int out_size, void* d_ws, size_t ws_size,
                              hipStream_t stream) {
  const float* Q = (const float*)d_in[0];
  const float* K = (const float*)d_in[1];
  const float* V = (const float*)d_in[2];
  float* O = (float*)d_out;

  const size_t need = 2 * NTOT * sizeof(unsigned short);
  if (ws_size >= need) {
    unsigned short* Kb = (unsigned short*)d_ws;
    unsigned short* Vt = Kb + NTOT;
    prep_kernel<<<dim3(2048), dim3(256), 0, stream>>>(K, V, Kb, Vt);
    mha_fwd_db2<<<dim3(2048), dim3(256), 0, stream>>>(Q, Kb, Vt, O);
  } else {
    mha_fwd_f32<<<dim3(2048), dim3(256), 0, stream>>>(Q, K, V, O);
  }
}

// Round 23
// 87.880 us; speedup vs baseline: 3.3100x; 1.0110x over previous
//
#include <hip/hip_runtime.h>
#include <hip/hip_bf16.h>

typedef __attribute__((ext_vector_type(8))) short bfrag8;           // 8 bf16
typedef __attribute__((ext_vector_type(8))) unsigned short u16x8;
typedef __attribute__((ext_vector_type(4))) float f32x4;
typedef __attribute__((ext_vector_type(16))) float f32x16;          // 32x32 MFMA C/D
typedef __attribute__((ext_vector_type(4))) unsigned int u32x4;

static constexpr int L_ = 2048;
static constexpr int H_ = 16;
static constexpr int D_ = 64;
static constexpr int ROWSTRIDE = H_ * D_;
static constexpr int BSTRIDE = L_ * H_ * D_;
static constexpr size_t NPH = (size_t)L_ * D_;
static constexpr size_t NTOT = (size_t)4 * H_ * L_ * D_;

// Finite "minus infinity" for masking (exp2(NEG - FIXM) == 0 exactly).
static constexpr float NEG = -1e30f;
// Fixed softmax reference max (exp2 domain); normalizer cancels in O = PV/l.
static constexpr float FIXM = 24.0f;
// (1/sqrt(D)) * log2(e): folded into Q at load time -> scores in exp2 domain.
static constexpr float QS = 0.125f * 1.44269504088896341f;

__device__ __forceinline__ unsigned short f2bf(float f) {
  return __builtin_bit_cast(unsigned short, __float2bfloat16(f));
}
__device__ __forceinline__ unsigned int pack2(float lo, float hi) {
  return (unsigned int)f2bf(lo) | ((unsigned int)f2bf(hi) << 16);
}

// Cross-half (lane i <-> i+32) sum via permlane32_swap builtin (verified r6).
__device__ __forceinline__ float crosshalf_sum(float x) {
  const unsigned xu = __builtin_bit_cast(unsigned int, x);
  auto r = __builtin_amdgcn_permlane32_swap(xu, xu, false, false);
  return __builtin_bit_cast(float, (unsigned int)r[0]) +
         __builtin_bit_cast(float, (unsigned int)r[1]);
}

// ---------------------------------------------------------------------------
// Prep: f32 [B,L,H,D] -> bf16 Kb[B,H,L,D], Vt[B,H,D,L].  (Q not prepped.)
// ---------------------------------------------------------------------------
__global__ __launch_bounds__(256, 4)
void prep_kernel(const float* __restrict__ K, const float* __restrict__ V,
                 unsigned short* __restrict__ Kb, unsigned short* __restrict__ Vt) {
  const int bid = blockIdx.x;
  const int lt = bid & 31;
  const int bh = bid >> 5;
  const int h = bh & 15;
  const int b = bh >> 4;
  const int l0 = lt * 64;
  const int t = threadIdx.x;
  const int lr = t >> 2;
  const int dc = t & 3;

  __shared__ __align__(16) unsigned short vt[64 * 64];

  const size_t src = ((size_t)(b * L_ + l0 + lr) * H_ + h) * D_ + dc * 16;
  const size_t dst = ((size_t)bh * L_ + l0 + lr) * D_ + dc * 16;

  {
    f32x4 a = *(const f32x4*)(K + src),     b4 = *(const f32x4*)(K + src + 4),
          c4 = *(const f32x4*)(K + src + 8), d4 = *(const f32x4*)(K + src + 12);
    u16x8 o0, o1;
#pragma unroll
    for (int j = 0; j < 4; ++j) {
      o0[j] = f2bf(a[j]);  o0[j + 4] = f2bf(b4[j]);
      o1[j] = f2bf(c4[j]); o1[j + 4] = f2bf(d4[j]);
    }
    *(u16x8*)(Kb + dst) = o0;
    *(u16x8*)(Kb + dst + 8) = o1;
  }
  {
    f32x4 a = *(const f32x4*)(V + src),     b4 = *(const f32x4*)(V + src + 4),
          c4 = *(const f32x4*)(V + src + 8), d4 = *(const f32x4*)(V + src + 12);
    u16x8 o0, o1;
#pragma unroll
    for (int j = 0; j < 4; ++j) {
      o0[j] = f2bf(a[j]);  o0[j + 4] = f2bf(b4[j]);
      o1[j] = f2bf(c4[j]); o1[j + 4] = f2bf(d4[j]);
    }
    const int r7 = (lr + (lr >> 3)) & 7;
    *(u16x8*)&vt[lr * 64 + (((dc * 2) ^ r7) * 8)] = o0;
    *(u16x8*)&vt[lr * 64 + (((dc * 2 + 1) ^ r7) * 8)] = o1;
  }
  __syncthreads();
  {
    const int d = t >> 2;
    const int lc = t & 3;
    const int ch = d >> 3, dl = d & 7;
    u16x8 o0, o1;
#pragma unroll
    for (int i = 0; i < 8; ++i) {
      const int r0 = lc * 16 + i;
      const int r1 = lc * 16 + 8 + i;
      o0[i] = vt[r0 * 64 + ((ch ^ ((r0 + (r0 >> 3)) & 7)) * 8) + dl];
      o1[i] = vt[r1 * 64 + ((ch ^ ((r1 + (r1 >> 3)) & 7)) * 8) + dl];
    }
    const size_t vd = ((size_t)bh * D_ + d) * L_ + l0 + lc * 16;
    *(u16x8*)(Vt + vd) = o0;
    *(u16x8*)(Vt + vd + 8) = o1;
  }
}

// ---------------------------------------------------------------------------
// Pair-block staged-LDS flash attention (r22 + COALESCED Q prologue).
// r22's f32 Q gather prologue (lane strides 4KB -> 32-line gathers, 4.2M line
// transactions in a burst) cost +6us. Fix: stage the block's 64 contiguous
// Q rows (16KB f32) into LDS with fully coalesced 16B chunks (4/thread),
// padded rows (68 f32) for the fragment reads, then cvt+scale in-reg.
// kv pair-0 loads are issued BEFORE Q staging and written after (T14).
// Hot loop byte-identical to r21/r22: pair of kv-tiles per iter, 32KB double
// buffer, issue-early -> QK -> release staged regs -> softmax+PV -> 1 barrier.
// Grid 2048 (backfill), longest-first, 2-way kv merge = pure adds.
// All LDS addresses arithmetic (r19 erratum). launch_bounds(256,4): VGPR 64.
// NEVER tighten the cap (r17). Spill tripwire: WRITE_SIZE >> 33MB.
// ---------------------------------------------------------------------------
__global__ __launch_bounds__(256, 4)
void mha_fwd_db2(const float* __restrict__ Qf,
                 const unsigned short* __restrict__ Kb,
                 const unsigned short* __restrict__ Vt,
                 float* __restrict__ Op) {
  const int bid = blockIdx.x;
  const int plane = bid & 63;               // b*16 + h
  const int p = 31 - (bid >> 6);            // q-tile pair index, longest first
  const int h = plane & 15;
  const int b = plane >> 4;

  const int tid = threadIdx.x;
  const int wv = tid >> 6;
  const int qsel = wv >> 1;                 // 0 -> qt=2p, 1 -> qt=2p+1
  const int pr = wv & 1;                    // kv-tile parity for this wave
  const int lane = tid & 63;
  const int q = lane & 31;
  const int hi = lane >> 5;

  const int qt = 2 * p + qsel;
  const int qr0 = qt * 32;
  const int P = p + 1;                      // iterations (2 kv-tiles each)

  // 32KB double-buffered pair staging; K slab [buf*2+tile]*4096, V at +16384.
  // Prologue transiently overlays arena[0..17408) as f32 qstage[64][68].
  __shared__ __align__(16) unsigned char arena[32768];
  float* mrg = (float*)arena;                          // [2][32][68] f32
  float* lshp = (float*)(arena + 17408);               // [2][32] f32
  float* qstage = (float*)arena;                       // [64][68] f32 (prologue)

  const unsigned short* Kh = Kb + (size_t)plane * NPH;
  const unsigned short* Vh = Vt + (size_t)plane * NPH;
  float* Ob = Op + (size_t)b * BSTRIDE + (size_t)h * D_;

  // staging roles (fixed per thread), XOR-chunk swizzle (write == read)
  const int kr = tid >> 3, kc = tid & 7;    // K: row 0..31, 16B chunk 0..7
  const int vr = tid >> 2, vc = tid & 3;    // V^T: row 0..63, 16B chunk 0..3
  const int kOff = kr * 64 + ((kc ^ (kr & 7)) * 8);   // elements
  const int vOff = vr * 32 + ((vc ^ (vr & 3)) * 8);

  // ---- prologue: kv pair-0 loads issued FIRST (written to LDS later) ----
  u16x8 k0 = *(const u16x8*)(Kh + (size_t)kr * D_ + kc * 8);
  u16x8 v0 = *(const u16x8*)(Vh + (size_t)vr * L_ + vc * 8);
  u16x8 k1 = *(const u16x8*)(Kh + (size_t)(32 + kr) * D_ + kc * 8);
  u16x8 v1 = *(const u16x8*)(Vh + (size_t)vr * L_ + 32 + vc * 8);

  // ---- coalesced Q staging: 64 rows x 256B; 1024 chunks, 4 per thread ----
  {
    const float* qbase = Qf + ((size_t)(b * L_ + 64 * p)) * ROWSTRIDE + h * D_;
#pragma unroll
    for (int i = 0; i < 4; ++i) {
      const int c4 = tid + 256 * i;         // chunk id 0..1023
      const int row = c4 >> 4;              // 0..63
      const int cin = c4 & 15;              // 16B chunk within row
      const f32x4 v = *(const f32x4*)(qbase + (size_t)row * ROWSTRIDE + cin * 4);
      *(f32x4*)&qstage[row * 68 + cin * 4] = v;
    }
  }
  __syncthreads();

  // Q B-frags from LDS (cvt+scale in-reg): lane holds Q[qr0+q][16s+8hi+j]
  bfrag8 qB[4];
#pragma unroll
  for (int s = 0; s < 4; ++s) {
    const float* qrow = &qstage[(qsel * 32 + q) * 68 + 16 * s + 8 * hi];
    const f32x4 lo = *(const f32x4*)qrow;
    const f32x4 hi4 = *(const f32x4*)(qrow + 4);
    bfrag8 f;
#pragma unroll
    for (int j = 0; j < 4; ++j) {
      f[j]     = (short)f2bf(lo[j] * QS);
      f[j + 4] = (short)f2bf(hi4[j] * QS);
    }
    qB[s] = f;
  }
  __syncthreads();                           // qstage dead; arena -> kv slabs

  // write kv pair 0 into buf 0
  {
    *(u16x8*)((unsigned short*)(arena) + kOff) = k0;
    *(u16x8*)((unsigned short*)(arena + 4096) + kOff) = k1;
    *(u16x8*)((unsigned short*)(arena + 16384) + vOff) = v0;
    *(u16x8*)((unsigned short*)(arena + 16384 + 4096) + vOff) = v1;
  }
  __syncthreads();

  float lp = 0.f;
  f32x16 o0 = {};                            // O[q][d = crow + 0..31]
  f32x16 o1 = {};                            // O[q][d = crow + 32..63]

  for (int k = 0; k < P; ++k) {
    const int cur = k & 1;
    const int t = 2 * k + pr;                // my kv-tile this iteration
    const bool more = (k + 1 < P);
    const bool docomp = (t <= qt);

    // 1) issue next pair's global loads
    u16x8 kn0, vn0, kn1, vn1;
    if (more) {
      const int base = (k + 1) * 64;         // rows of tile 2k+2
      kn0 = *(const u16x8*)(Kh + (size_t)(base + kr) * D_ + kc * 8);
      vn0 = *(const u16x8*)(Vh + (size_t)vr * L_ + base + vc * 8);
      kn1 = *(const u16x8*)(Kh + (size_t)(base + 32 + kr) * D_ + kc * 8);
      vn1 = *(const u16x8*)(Vh + (size_t)vr * L_ + base + 32 + vc * 8);
    }

    // 2) QK MFMA (loads land underneath; V-frag reads deferred)
    f32x16 sacc = {};
    if (docomp) {
      const unsigned short* kb =
          (const unsigned short*)(arena + (size_t)(cur * 2 + pr) * 4096);
      bfrag8 kA[4];
#pragma unroll
      for (int s = 0; s < 4; ++s)
        kA[s] = *(const bfrag8*)&kb[q * 64 + (((2 * s + hi) ^ (q & 7)) * 8)];
      __builtin_amdgcn_s_setprio(1);
#pragma unroll
      for (int s = 0; s < 4; ++s)
        sacc = __builtin_amdgcn_mfma_f32_32x32x16_bf16(kA[s], qB[s], sacc, 0, 0, 0);
      __builtin_amdgcn_s_setprio(0);
    }

    // 3) RELEASE staged regs: write into the other buffer NOW (regs die here,
    //    before softmax/PV; target buffer's readers finished last iteration)
    if (more) {
      unsigned char* kslab = arena + (size_t)((cur ^ 1) * 2) * 4096;
      unsigned char* vslab = arena + 16384 + (size_t)((cur ^ 1) * 2) * 4096;
      *(u16x8*)((unsigned short*)kslab + kOff) = kn0;
      *(u16x8*)((unsigned short*)(kslab + 4096) + kOff) = kn1;
      *(u16x8*)((unsigned short*)vslab + vOff) = vn0;
      *(u16x8*)((unsigned short*)(vslab + 4096) + vOff) = vn1;
    }

    // 4) softmax + PV (V-frags read here, after the release)
    if (docomp) {
      if (t == qt) {
#pragma unroll
        for (int r = 0; r < 16; ++r) {
          const int crow = (r & 3) + 8 * (r >> 2) + 4 * hi;
          if (crow > q) sacc[r] = NEG;
        }
      }

#pragma unroll
      for (int r = 0; r < 16; ++r) sacc[r] = __builtin_exp2f(sacc[r] - FIXM);
      {
        float s8[8];
#pragma unroll
        for (int r = 0; r < 8; ++r) s8[r] = sacc[2 * r] + sacc[2 * r + 1];
#pragma unroll
        for (int r = 0; r < 4; ++r) s8[r] += s8[r + 4];
        lp += (s8[0] + s8[2]) + (s8[1] + s8[3]);
      }

      const unsigned int a0 = pack2(sacc[0],  sacc[1]),  a1 = pack2(sacc[2],  sacc[3]);
      const unsigned int a2 = pack2(sacc[4],  sacc[5]),  a3 = pack2(sacc[6],  sacc[7]);
      const unsigned int a4 = pack2(sacc[8],  sacc[9]),  a5 = pack2(sacc[10], sacc[11]);
      const unsigned int a6 = pack2(sacc[12], sacc[13]), a7 = pack2(sacc[14], sacc[15]);
      auto r02 = __builtin_amdgcn_permlane32_swap(a0, a2, false, false);
      auto r13 = __builtin_amdgcn_permlane32_swap(a1, a3, false, false);
      auto r46 = __builtin_amdgcn_permlane32_swap(a4, a6, false, false);
      auto r57 = __builtin_amdgcn_permlane32_swap(a5, a7, false, false);
      u32x4 w0, w1;
      w0[0] = r02[0]; w0[1] = r13[0]; w0[2] = r02[1]; w0[3] = r13[1];
      w1[0] = r46[0]; w1[1] = r57[0]; w1[2] = r46[1]; w1[3] = r57[1];
      const bfrag8 pb0 = __builtin_bit_cast(bfrag8, w0);
      const bfrag8 pb1 = __builtin_bit_cast(bfrag8, w1);

      const unsigned short* vb =
          (const unsigned short*)(arena + 16384 + (size_t)(cur * 2 + pr) * 4096);
      bfrag8 vA[2][2];
#pragma unroll
      for (int ks = 0; ks < 2; ++ks)
#pragma unroll
        for (int dh = 0; dh < 2; ++dh)
          vA[ks][dh] = *(const bfrag8*)&vb[(32 * dh + q) * 32 + (((2 * ks + hi) ^ (q & 3)) * 8)];

      __builtin_amdgcn_s_setprio(1);
      o0 = __builtin_amdgcn_mfma_f32_32x32x16_bf16(vA[0][0], pb0, o0, 0, 0, 0);
      o0 = __builtin_amdgcn_mfma_f32_32x32x16_bf16(vA[1][0], pb1, o0, 0, 0, 0);
      o1 = __builtin_amdgcn_mfma_f32_32x32x16_bf16(vA[0][1], pb0, o1, 0, 0, 0);
      o1 = __builtin_amdgcn_mfma_f32_32x32x16_bf16(vA[1][1], pb1, o1, 0, 0, 0);
      __builtin_amdgcn_s_setprio(0);
    }

    // 5) one barrier per iter: publishes buf[cur^1], fences reads of buf[cur]
    __syncthreads();
  }

  // ---- 2-way kv merge per q-tile (pure adds; arena overlaid) ----
  const float lfull = crosshalf_sum(lp);
  float* mrow = mrg + (qsel * 32 + q) * 68;
  if (pr == 1) {
#pragma unroll
    for (int r2 = 0; r2 < 4; ++r2) {
      f32x4 s0, s1;
#pragma unroll
      for (int j = 0; j < 4; ++j) { s0[j] = o0[4 * r2 + j]; s1[j] = o1[4 * r2 + j]; }
      *(f32x4*)&mrow[8 * r2 + 4 * hi] = s0;
      *(f32x4*)&mrow[32 + 8 * r2 + 4 * hi] = s1;
    }
    if (hi == 0) lshp[qsel * 32 + q] = lfull;
  }
  __syncthreads();
  if (pr == 0) {
    const float inv = 1.f / (lfull + lshp[qsel * 32 + q]);
    float* orow = Ob + (size_t)(qr0 + q) * ROWSTRIDE;
#pragma unroll
    for (int r2 = 0; r2 < 4; ++r2) {
      const f32x4 pB0 = *(const f32x4*)&mrow[8 * r2 + 4 * hi];
      const f32x4 pB1 = *(const f32x4*)&mrow[32 + 8 * r2 + 4 * hi];
      f32x4 s0, s1;
#pragma unroll
      for (int j = 0; j < 4; ++j) {
        s0[j] = (o0[4 * r2 + j] + pB0[j]) * inv;
        s1[j] = (o1[4 * r2 + j] + pB1[j]) * inv;
      }
      *(f32x4*)(orow + 8 * r2 + 4 * hi) = s0;
      *(f32x4*)(orow + 32 + 8 * r2 + 4 * hi) = s1;
    }
  }
}

// ---------------------------------------------------------------------------
// Fallback if workspace too small (f32 direct; natural-exp domain)
// ---------------------------------------------------------------------------
__global__ __launch_bounds__(256, 4)
void mha_fwd_f32(const float* __restrict__ Qp, const float* __restrict__ Kp,
                 const float* __restrict__ Vp, float* __restrict__ Op) {
  const int bid = blockIdx.x;
  const int qt = 31 - (bid & 31);
  const int bh = bid >> 5;
  const int h = bh & 15;
  const int b = bh >> 4;
  const int tid = threadIdx.x;
  const int w = tid >> 6;
  const int lane = tid & 63;
  const int g = lane >> 4;
  const int c = lane & 15;

  __shared__ __align__(16) unsigned short Pb[4][16 * 64];
  unsigned short* P = Pb[w];

  const size_t base = (size_t)b * BSTRIDE + (size_t)h * D_;
  const float* Qb = Qp + base;
  const float* Kb = Kp + base;
  const float* Vb = Vp + base;
  float* Ob = Op + base;
  const int qr0 = qt * 64 + w * 16;

  bfrag8 qf[2];
  {
    const float* qp = Qb + (size_t)(qr0 + c) * ROWSTRIDE + g * 8;
#pragma unroll
    for (int s = 0; s < 2; ++s) {
      f32x4 a0 = *(const f32x4*)(qp + 32 * s);
      f32x4 a1 = *(const f32x4*)(qp + 32 * s + 4);
      bfrag8 f;
#pragma unroll
      for (int j = 0; j < 4; ++j) {
        f[j] = (short)f2bf(a0[j] * 0.125f);
        f[j + 4] = (short)f2bf(a1[j] * 0.125f);
      }
      qf[s] = f;
    }
  }
  float m_i[4], l_i[4];
  f32x4 oacc[4];
#pragma unroll
  for (int i = 0; i < 4; ++i) {
    m_i[i] = -INFINITY; l_i[i] = 0.f;
    oacc[i][0] = oacc[i][1] = oacc[i][2] = oacc[i][3] = 0.f;
  }
  for (int t = 0; t <= qt; ++t) {
    const int kv0 = t * 64;
    const bool diag = (t == qt);
    const int kbmax = diag ? w : 3;
    f32x4 sacc[4];
#pragma unroll
    for (int kb = 0; kb < 4; ++kb) {
      if (kb <= kbmax) {
        f32x4 acc; acc[0] = acc[1] = acc[2] = acc[3] = 0.f;
        const float* kp = Kb + (size_t)(kv0 + kb * 16 + c) * ROWSTRIDE + g * 8;
#pragma unroll
        for (int s = 0; s < 2; ++s) {
          f32x4 a0 = *(const f32x4*)(kp + 32 * s);
          f32x4 a1 = *(const f32x4*)(kp + 32 * s + 4);
          bfrag8 kf;
#pragma unroll
          for (int j = 0; j < 4; ++j) {
            kf[j] = (short)f2bf(a0[j]);
            kf[j + 4] = (short)f2bf(a1[j]);
          }
          acc = __builtin_amdgcn_mfma_f32_16x16x32_bf16(qf[s], kf, acc, 0, 0, 0);
        }
        if (diag && kb == w) {
#pragma unroll
          for (int i = 0; i < 4; ++i)
            if (c > 4 * g + i) acc[i] = -INFINITY;
        }
        sacc[kb] = acc;
      } else {
        sacc[kb][0] = sacc[kb][1] = sacc[kb][2] = sacc[kb][3] = -INFINITY;
      }
    }
    float tmax[4];
#pragma unroll
    for (int i = 0; i < 4; ++i)
      tmax[i] = fmaxf(fmaxf(sacc[0][i], sacc[1][i]), fmaxf(sacc[2][i], sacc[3][i]));
#pragma unroll
    for (int mk = 1; mk <= 8; mk <<= 1)
#pragma unroll
      for (int i = 0; i < 4; ++i) tmax[i] = fmaxf(tmax[i], __shfl_xor(tmax[i], mk));
    float rsum[4];
#pragma unroll
    for (int i = 0; i < 4; ++i) {
      const float mnew = fmaxf(m_i[i], tmax[i]);
      const float sc = __expf(m_i[i] - mnew);
      m_i[i] = mnew;
      float rs = 0.f;
#pragma unroll
      for (int kb = 0; kb < 4; ++kb) {
        const float p = __expf(sacc[kb][i] - mnew);
        sacc[kb][i] = p; rs += p;
      }
      rsum[i] = rs; l_i[i] *= sc;
#pragma unroll
      for (int db = 0; db < 4; ++db) oacc[db][i] *= sc;
    }
#pragma unroll
    for (int mk = 1; mk <= 8; mk <<= 1)
#pragma unroll
      for (int i = 0; i < 4; ++i) rsum[i] += __shfl_xor(rsum[i], mk);
#pragma unroll
    for (int i = 0; i < 4; ++i) l_i[i] += rsum[i];
#pragma unroll
    for (int kb = 0; kb < 4; ++kb) {
      const int col = kb * 16 + c;
      const int chunk = col >> 3;
      const int lo = col & 7;
#pragma unroll
      for (int i = 0; i < 4; ++i) {
        const int row = 4 * g + i;
        P[row * 64 + ((chunk ^ (row & 7)) * 8) + lo] = f2bf(sacc[kb][i]);
      }
    }
    asm volatile("s_waitcnt lgkmcnt(0)" ::: "memory");
    bfrag8 pa[2];
#pragma unroll
    for (int ks = 0; ks < 2; ++ks) {
      const int row = c;
      const int chunk = (4 * ks + g) ^ (row & 7);
      pa[ks] = *(const bfrag8*)&P[row * 64 + chunk * 8];
    }
#pragma unroll
    for (int ks = 0; ks < 2; ++ks) {
      const float* vp = Vb + (size_t)(kv0 + ks * 32 + g * 8) * ROWSTRIDE + c;
#pragma unroll
      for (int db = 0; db < 4; ++db) {
        bfrag8 vf;
#pragma unroll
        for (int j = 0; j < 8; ++j)
          vf[j] = (short)f2bf(vp[(size_t)j * ROWSTRIDE + db * 16]);
        oacc[db] = __builtin_amdgcn_mfma_f32_16x16x32_bf16(pa[ks], vf, oacc[db], 0, 0, 0);
      }
    }
  }
#pragma unroll
  for (int i = 0; i < 4; ++i) {
    const float inv = 1.f / l_i[i];
    const int qq = qr0 + 4 * g + i;
    float* op = Ob + (size_t)qq * ROWSTRIDE + c;
#pragma unroll
    for (int db = 0; db < 4; ++db)
      op[db * 16] = oacc[db][i] * inv;
  }
}

extern "C" void kernel_launch(void* const* d_in, const int* in_sizes, int n_in,
                              void* d_out, int out_size, void* d_ws, size_t ws_size,
                              hipStream_t stream) {
  const float* Q = (const float*)d_in[0];
  const float* K = (const float*)d_in[1];
  const float* V = (const float*)d_in[2];
  float* O = (float*)d_out;

  const size_t need = 2 * NTOT * sizeof(unsigned short);
  if (ws_size >= need) {
    unsigned short* Kb = (unsigned short*)d_ws;
    unsigned short* Vt = Kb + NTOT;
    prep_kernel<<<dim3(2048), dim3(256), 0, stream>>>(K, V, Kb, Vt);
    mha_fwd_db2<<<dim3(2048), dim3(256), 0, stream>>>(Q, Kb, Vt, O);
  } else {
    mha_fwd_f32<<<dim3(2048), dim3(256), 0, stream>>>(Q, K, V, O);
  }
}